// Round 7
// baseline (376.020 us; speedup 1.0000x reference)
//
#include <hip/hip_runtime.h>
#include <hip/hip_bf16.h>

// ---------------------------------------------------------------------------
// SelfAttentionHybrid: single-head attention, B=4 S=2048 E=1024, fp32 in/out.
// R13: (a) revert gemm256 to R10 config (16x16 MFMA, counted-lgkm ladder,
// 1 barrier/tile) -- R12's 32x32 shape created a STRUCTURAL 4-way LDS bank
// conflict (32 rows/instr vs 8-slot XOR space; bank = f(slot) only), counter
// went 0 -> 4.7M = +4cy/read, QKV 62.3 -> 67.2.
// (b) algebraic K-elimination: softmax is shift-invariant per row, so
//   S = q.k^T == x.M.x^T + v.x^T (+row-const)  with M = Wq^T.Wk, v = bq.Wk.
// Fused projection computes [G|V] (N=2048, grid 8x32 = 256 blocks = ONE
// dispatch round) with G = x.M + v; scores = gemm_bt(G, xb) * E^-0.5.
// Precompute: WqT/WkT transposes + MT = Wk^T.Wq (gemm_bt on 64 blocks) +
// v-vector kernel. Saves a full 8192x1024x1024 projection leg (~31us gross).
// Numerics: extra bf16 rounding of M -> absmax expected ~1.3-1.5x baseline.
// ---------------------------------------------------------------------------

typedef __bf16 bf16_t;
typedef __bf16 bf16x8 __attribute__((ext_vector_type(8)));
typedef __bf16 bf16x4 __attribute__((ext_vector_type(4)));
typedef float  f32x16 __attribute__((ext_vector_type(16)));
typedef float  f32x4  __attribute__((ext_vector_type(4)));

__device__ __forceinline__ void async_copy16(const void* g, void* l) {
  __builtin_amdgcn_global_load_lds(
      (const __attribute__((address_space(1))) void*)g,
      (__attribute__((address_space(3))) void*)l, 16, 0, 0);
}

// raw workgroup barrier: NO vmcnt/lgkmcnt drain (unlike __syncthreads).
__device__ __forceinline__ void wg_barrier() {
  asm volatile("" ::: "memory");
  __builtin_amdgcn_s_barrier();
  asm volatile("" ::: "memory");
}

// counted LDS wait + rule-18 scheduler pin (MFMAs must not hoist above it)
#define LGKM(n)                                                  \
  do {                                                           \
    asm volatile("s_waitcnt lgkmcnt(" #n ")" ::: "memory");      \
    __builtin_amdgcn_sched_barrier(0);                           \
  } while (0)

#define VM(n) asm volatile("s_waitcnt vmcnt(" #n ")" ::: "memory")

// 32-bit LDS byte address (for asm ds_read; invisible to alias analysis)
__device__ __forceinline__ unsigned lds_addr(const void* p) {
  return (unsigned)(unsigned long long)(__attribute__((address_space(3))) const void*)p;
}

// inline-asm LDS read: compiler cannot see this as an LDS access, so it does
// NOT insert vmcnt(0) ordering vs in-flight global_load_lds prefetches.
// Ordering enforced manually via LGKM() + the per-tile vmcnt/barrier.
__device__ __forceinline__ bf16x8 ds_read128(const bf16_t* p) {
  bf16x8 r;
  asm volatile("ds_read_b128 %0, %1" : "=v"(r) : "v"(lds_addr(p)));
  return r;
}

__device__ __forceinline__ f32x4 mfma16(bf16x8 a, bf16x8 b, f32x4 c) {
  return __builtin_amdgcn_mfma_f32_16x16x32_bf16(a, b, c, 0, 0, 0);
}

__device__ __forceinline__ void store_out(float* p, float v)  { *p = v; }
__device__ __forceinline__ void store_out(bf16_t* p, float v) { *p = (bf16_t)v; }

#define BM 128
#define BN 128
#define BKT 64

// 4 MFMA: a[i] x bb -> acc[ro+i][co..co+1], both k-slices
#define G_AQ(i, ro, bb, co)                                                   \
  acc[(ro) + (i)][(co) + 0] = mfma16(a[i][0], bb[0][0], acc[(ro) + (i)][(co) + 0]); \
  acc[(ro) + (i)][(co) + 1] = mfma16(a[i][0], bb[1][0], acc[(ro) + (i)][(co) + 1]); \
  acc[(ro) + (i)][(co) + 0] = mfma16(a[i][1], bb[0][1], acc[(ro) + (i)][(co) + 0]); \
  acc[(ro) + (i)][(co) + 1] = mfma16(a[i][1], bb[1][1], acc[(ro) + (i)][(co) + 1]);

// 8 MFMA: all a[i] x bb[j] -> acc[0..3][co+j], both k-slices
#define G_BQ(j, bb, co)                                              \
  acc[0][(co) + (j)] = mfma16(a[0][0], bb[j][0], acc[0][(co) + (j)]); \
  acc[1][(co) + (j)] = mfma16(a[1][0], bb[j][0], acc[1][(co) + (j)]); \
  acc[2][(co) + (j)] = mfma16(a[2][0], bb[j][0], acc[2][(co) + (j)]); \
  acc[3][(co) + (j)] = mfma16(a[3][0], bb[j][0], acc[3][(co) + (j)]); \
  acc[0][(co) + (j)] = mfma16(a[0][1], bb[j][1], acc[0][(co) + (j)]); \
  acc[1][(co) + (j)] = mfma16(a[1][1], bb[j][1], acc[1][(co) + (j)]); \
  acc[2][(co) + (j)] = mfma16(a[2][1], bb[j][1], acc[2][(co) + (j)]); \
  acc[3][(co) + (j)] = mfma16(a[3][1], bb[j][1], acc[3][(co) + (j)]);

// ---------------------------------------------------------------------------
// gemm256_bt (R10 config): C[M,N] = A[M,K](lda) x B[N,K](ldb)^T * scale + b.
// 512 thr = 8 waves (2Mx4N); wave tile 128x64 = 8x4 frags of 16x16x32 MFMA.
// LDS [2 buf][256 rows][64 bf16] per matrix; slot (r,cc) holds global chunk
// cc^(r&7); reads use slot kc^(r&7) (involution; 16-row instrs => 2-way max,
// measured 0 conflicts).
// Requires M%256==0, N%256==0, K%128==0 (NT even), gridDim.y%8==0.
// ---------------------------------------------------------------------------
template <typename OutT, int NBIAS>
__global__ __launch_bounds__(512, 2) void gemm256_bt(
    const bf16_t* __restrict__ A, const bf16_t* __restrict__ B,
    OutT* __restrict__ C,
    const float* __restrict__ b0, const float* __restrict__ b1,
    const float* __restrict__ b2,
    int M, int N, int K, int lda, int ldb, int ldc, float scale,
    long long strideA, long long strideB, long long strideC) {
  const int z = blockIdx.z;
  A += (long long)z * strideA;
  B += (long long)z * strideB;
  C += (long long)z * strideC;

  // L2 supertile remap: 8 y-tiles per supertile, y-fastest inside.
  int bx = blockIdx.x, by = blockIdx.y;
  {
    const int GX  = gridDim.x;
    const int id  = by * GX + bx;
    const int per = GX * 8;
    const int grp = id / per;
    const int rem = id - grp * per;
    by = grp * 8 + (rem & 7);
    bx = rem >> 3;
  }

  __shared__ __align__(16) bf16_t As[2 * 256 * 64];  // 64 KB
  __shared__ __align__(16) bf16_t Bs[2 * 256 * 64];  // 64 KB

  const int t    = threadIdx.x;
  const int lane = t & 63;
  const int w    = t >> 6;
  const int wm   = w & 1;    // M-half of output tile
  const int wn   = w >> 1;   // N-quarter of output tile
  const int g    = lane >> 4;
  const int l7   = lane & 7;
  const int r15  = lane & 15;
  const int tileM = by * 256;
  const int tileN = bx * 256;

  // staging constants: thread covers chunks t and t+512 of each half-tile
  const int row0 = t >> 3;                    // 0..63
  const int gcc  = (t & 7) ^ (row0 & 7);      // swizzled source chunk
  const int dstb = (t & ~63) * 8;             // wave-uniform LDS base (elems)

  // read constants
  const int sw0 = ((0 + g) ^ l7) * 8;         // k-slice 0 chunk offset (elems)
  const int sw1 = ((4 + g) ^ l7) * 8;         // k-slice 1
  const int aRow = (wm * 128 + r15) * 64;
  const int bRow = (wn * 64 + r15) * 64;

  const int NT = K >> 6;

  f32x4 acc[8][4] = {};

  auto stageA = [&](int kt, int h) {
    const int cb = (kt & 1) * 16384;
    const bf16_t* src =
        A + (long long)(tileM + h * 128 + row0) * lda + kt * 64 + gcc * 8;
    bf16_t* dst = &As[cb + h * 8192 + dstb];
    async_copy16(src, dst);
    async_copy16(src + (long long)64 * lda, dst + 4096);
  };
  auto stageB = [&](int kt, int h) {
    const int cb = (kt & 1) * 16384;
    const bf16_t* src =
        B + (long long)(tileN + h * 128 + row0) * ldb + kt * 64 + gcc * 8;
    bf16_t* dst = &Bs[cb + h * 8192 + dstb];
    async_copy16(src, dst);
    async_copy16(src + (long long)64 * ldb, dst + 4096);
  };

  // prologue: stage tile 0 only; retire; pre-read B0(0) (4 reads stay
  // outstanding into tile 0 ph0 -- steady-state invariant).
  stageA(0, 0); stageA(0, 1); stageB(0, 0); stageB(0, 1);
  VM(0);
  wg_barrier();

  bf16x8 a[4][2], P[2][2], Q[2][2];
#pragma unroll
  for (int j = 0; j < 2; ++j) {
    P[j][0] = ds_read128(&Bs[bRow + j * 1024 + sw0]);
    P[j][1] = ds_read128(&Bs[bRow + j * 1024 + sw1]);
  }

  // bc = B0(kt) (read at prev ph3); bq = scratch: gets B1(kt) then B0(kt+1)
  auto tile_step = [&](int kt, bf16x8 (&bc)[2][2], bf16x8 (&bq)[2][2]) {
    const int cb = (kt & 1) * 16384;
    const int kn = kt + 1;
    const bf16_t* Ab = &As[cb + aRow];
    const bf16_t* Bb = &Bs[cb + bRow];

    // ---- ph0: issue A0 reads (outstanding 4+8=12); stage B(kt+1);
    //           MFMA M0N0 interleaved on counted lgkm.
#pragma unroll
    for (int i = 0; i < 4; ++i) {
      a[i][0] = ds_read128(Ab + i * 1024 + sw0);
      a[i][1] = ds_read128(Ab + i * 1024 + sw1);
    }
    if (kn < NT) { stageB(kn, 0); stageB(kn, 1); }
    __builtin_amdgcn_s_setprio(1);
    LGKM(6);  // retires B0(kt) x4 + a[0] pair
    G_AQ(0, 0, bc, 0)
    LGKM(4);
    G_AQ(1, 0, bc, 0)
    LGKM(2);
    G_AQ(2, 0, bc, 0)
    LGKM(0);
    G_AQ(3, 0, bc, 0)
    __builtin_amdgcn_s_setprio(0);

    // ---- ph1: issue B1 reads (4); stage A(kt+1); MFMA M0N1 interleaved.
#pragma unroll
    for (int j = 0; j < 2; ++j) {
      bq[j][0] = ds_read128(Bb + 2048 + j * 1024 + sw0);
      bq[j][1] = ds_read128(Bb + 2048 + j * 1024 + sw1);
    }
    if (kn < NT) { stageA(kn, 0); stageA(kn, 1); }
    __builtin_amdgcn_s_setprio(1);
    LGKM(2);  // bq[0] ready
    G_BQ(0, bq, 2)
    LGKM(0);  // bq[1] ready
    G_BQ(1, bq, 2)
    __builtin_amdgcn_s_setprio(0);

    // ---- ph2: issue A1 reads (8); MFMA M1N1 interleaved; then retire
    //           staging(kt+1) [exact: only those 8 in flight] + barrier.
#pragma unroll
    for (int i = 0; i < 4; ++i) {
      a[i][0] = ds_read128(Ab + 4096 + i * 1024 + sw0);
      a[i][1] = ds_read128(Ab + 4096 + i * 1024 + sw1);
    }
    __builtin_amdgcn_s_setprio(1);
    LGKM(6);
    G_AQ(0, 4, bq, 2)
    LGKM(4);
    G_AQ(1, 4, bq, 2)
    LGKM(2);
    G_AQ(2, 4, bq, 2)
    LGKM(0);
    G_AQ(3, 4, bq, 2)
    __builtin_amdgcn_s_setprio(0);
    VM(0);
    wg_barrier();  // buffer (kt+1)&1 now visible to all waves

    // ---- ph3: read B0(kt+1) -> bq (B1 dead; drains under next ph0's
    //           LGKM(6)); MFMA M1N0 -- all inputs resident, no wait.
    if (kn < NT) {
      const bf16_t* Bn = &Bs[(kn & 1) * 16384 + bRow];
#pragma unroll
      for (int j = 0; j < 2; ++j) {
        bq[j][0] = ds_read128(Bn + j * 1024 + sw0);
        bq[j][1] = ds_read128(Bn + j * 1024 + sw1);
      }
    }
    __builtin_amdgcn_s_setprio(1);
    G_AQ(0, 4, bc, 0)
    G_AQ(1, 4, bc, 0)
    G_AQ(2, 4, bc, 0)
    G_AQ(3, 4, bc, 0)
    __builtin_amdgcn_s_setprio(0);
  };

  for (int kt = 0; kt < NT; kt += 2) {
    tile_step(kt,     P, Q);   // bc = P holds B0(kt);   Q gets B1, B0(kt+1)
    tile_step(kt + 1, Q, P);   // bc = Q holds B0(kt+1); P gets B1, B0(kt+2)
  }

  // epilogue: 16x16 C map: col = lane&15, row = (lane>>4)*4 + r.
  // j innermost: 4 consecutive 32B segments per row -> 128B write-combining.
  float bvv[4];
#pragma unroll
  for (int j = 0; j < 4; ++j) {
    const int col = tileN + wn * 64 + j * 16 + r15;
    float bv = 0.f;
    if (NBIAS == 1) bv = b0[col];
    if (NBIAS == 3) {
      const float* bp = col < 1024 ? b0 : (col < 2048 ? b1 : b2);
      bv = bp[col & 1023];
    }
    bvv[j] = bv;
  }
#pragma unroll
  for (int i = 0; i < 8; ++i) {
#pragma unroll
    for (int r = 0; r < 4; ++r) {
      const long long row = tileM + wm * 128 + i * 16 + g * 4 + r;
      OutT* Crow = C + row * ldc + tileN + wn * 64 + r15;
#pragma unroll
      for (int j = 0; j < 4; ++j)
        store_out(Crow + j * 16, acc[i][j][r] * scale + bvv[j]);
    }
  }
}

// ---------------------------------------------------------------------------
// 128^2 kernel — PV, out-proj, and the small MT = Wk^T.Wq precompute.
// ---------------------------------------------------------------------------
template <typename OutT, int NBIAS>
__global__ __launch_bounds__(256) void gemm_bt(
    const bf16_t* __restrict__ A, const bf16_t* __restrict__ B,
    OutT* __restrict__ C,
    const float* __restrict__ b0, const float* __restrict__ b1,
    const float* __restrict__ b2,
    int M, int N, int K, int lda, int ldb, int ldc, float scale,
    long long strideA, long long strideB, long long strideC) {
  const int z = blockIdx.z;
  A += (long long)z * strideA;
  B += (long long)z * strideB;
  C += (long long)z * strideC;

  int bx = blockIdx.x, by = blockIdx.y;
  {
    const int GX  = gridDim.x;
    const int id  = by * GX + bx;
    const int per = GX * 8;
    const int grp = id / per;
    const int rem = id - grp * per;
    by = grp * 8 + (rem & 7);
    bx = rem >> 3;
  }

  __shared__ __align__(16) bf16_t As[BM * BKT];  // 16 KB
  __shared__ __align__(16) bf16_t Bs[BN * BKT];  // 16 KB

  const int t    = threadIdx.x;
  const int lane = t & 63;
  const int w    = t >> 6;
  const int wm   = w & 1;
  const int wn   = w >> 1;
  const int tileM = by * BM;
  const int tileN = bx * BN;

  f32x16 acc[2][2] = {};

  for (int k0 = 0; k0 < K; k0 += BKT) {
#pragma unroll
    for (int i = 0; i < 4; ++i) {
      const int c   = t + 256 * i;
      const int row = c >> 3;
      const int cc  = c & 7;
      const int gcc = cc ^ (row & 7);
      const int ldsbase = ((t & ~63) + 256 * i) * 8;
      async_copy16(A + (long long)(tileM + row) * lda + k0 + gcc * 8, &As[ldsbase]);
      async_copy16(B + (long long)(tileN + row) * ldb + k0 + gcc * 8, &Bs[ldsbase]);
    }
    __syncthreads();

#pragma unroll
    for (int s = 0; s < 4; ++s) {
      const int kc = s + 4 * (lane >> 5);
      bf16x8 af[2], bfr[2];
#pragma unroll
      for (int ti = 0; ti < 2; ++ti) {
        const int row = wm * 64 + ti * 32 + (lane & 31);
        af[ti] = *(const bf16x8*)&As[row * BKT + ((kc ^ (row & 7)) * 8)];
      }
#pragma unroll
      for (int tj = 0; tj < 2; ++tj) {
        const int row = wn * 64 + tj * 32 + (lane & 31);
        bfr[tj] = *(const bf16x8*)&Bs[row * BKT + ((kc ^ (row & 7)) * 8)];
      }
#pragma unroll
      for (int ti = 0; ti < 2; ++ti)
#pragma unroll
        for (int tj = 0; tj < 2; ++tj)
          acc[ti][tj] = __builtin_amdgcn_mfma_f32_32x32x16_bf16(
              af[ti], bfr[tj], acc[ti][tj], 0, 0, 0);
    }
    __syncthreads();
  }

#pragma unroll
  for (int tj = 0; tj < 2; ++tj) {
    const int col = tileN + wn * 64 + tj * 32 + (lane & 31);
    float bv = 0.f;
    if (NBIAS == 1) bv = b0[col];
    if (NBIAS == 3) {
      const float* bp = col < 1024 ? b0 : (col < 2048 ? b1 : b2);
      bv = bp[col & 1023];
    }
#pragma unroll
    for (int ti = 0; ti < 2; ++ti) {
      const int rowb = tileM + wm * 64 + ti * 32 + 4 * (lane >> 5);
#pragma unroll
      for (int r = 0; r < 16; ++r) {
        const int row = rowb + (r & 3) + 8 * (r >> 2);
        store_out(&C[(long long)row * ldc + col], acc[ti][tj][r] * scale + bv);
      }
    }
  }
}

// ---------------------------------------------------------------------------
// fused cast: 4 weights (separate dsts) + x in one dispatch.
// ---------------------------------------------------------------------------
__global__ __launch_bounds__(256) void cast_all(
    const float4* __restrict__ w0, const float4* __restrict__ w1,
    const float4* __restrict__ w2, const float4* __restrict__ w3,
    const float4* __restrict__ x,
    bf16x4* __restrict__ d0, bf16x4* __restrict__ d1,
    bf16x4* __restrict__ d2, bf16x4* __restrict__ d3,
    bf16x4* __restrict__ xdst) {
  const int N4W = 1 << 18;  // 1024*1024/4
  const int id = blockIdx.x * 256 + threadIdx.x;
  const float4* src;
  bf16x4* dst;
  if (id < 4 * N4W) {
    const int z = id >> 18;
    const int i = id & (N4W - 1);
    src = (z == 0 ? w0 : z == 1 ? w1 : z == 2 ? w2 : w3) + i;
    dst = (z == 0 ? d0 : z == 1 ? d1 : z == 2 ? d2 : d3) + i;
  } else {
    const int i = id - 4 * N4W;
    src = x + i;
    dst = xdst + i;
  }
  const float4 v = *src;
  bf16x4 o;
  o[0] = (bf16_t)v.x; o[1] = (bf16_t)v.y; o[2] = (bf16_t)v.z; o[3] = (bf16_t)v.w;
  *dst = o;
}

// ---------------------------------------------------------------------------
// v = bq . Wk  (v[j] = sum_c bq[c] * Wk[c,j]); fp32 inputs, fp32 out.
// ---------------------------------------------------------------------------
__global__ __launch_bounds__(256) void bias_v(
    const float* __restrict__ Wk, const float* __restrict__ bq,
    float* __restrict__ v) {
  const int j = blockIdx.x * 256 + threadIdx.x;  // grid 4 -> j in [0,1024)
  float acc = 0.f;
#pragma unroll 4
  for (int c = 0; c < 1024; ++c) acc += bq[c] * Wk[c * 1024 + j];
  v[j] = acc;
}

// ---------------------------------------------------------------------------
// bf16 transpose [R,C](ldin) -> [C,R], batched via blockIdx.z
// ---------------------------------------------------------------------------
__global__ __launch_bounds__(256) void transpose_bf16(
    const bf16_t* __restrict__ in, bf16_t* __restrict__ out, int R, int C,
    int ldin, long long sIn, long long sOut) {
  in  += (long long)blockIdx.z * sIn;
  out += (long long)blockIdx.z * sOut;
  __shared__ bf16_t tile[32][33];
  const int tx = threadIdx.x, ty = threadIdx.y;
  const int x = blockIdx.x * 32 + tx;
  const int y0 = blockIdx.y * 32;
#pragma unroll
  for (int j = 0; j < 32; j += 8)
    tile[ty + j][tx] = in[(long long)(y0 + ty + j) * ldin + x];
  __syncthreads();
  const int x2 = y0 + tx;
  const int y2 = blockIdx.x * 32;
#pragma unroll
  for (int j = 0; j < 32; j += 8)
    out[(long long)(y2 + ty + j) * R + x2] = tile[tx][ty + j];
}

// ---------------------------------------------------------------------------
// row softmax: 2048-wide rows, 256 threads x 8 elems
// ---------------------------------------------------------------------------
__global__ __launch_bounds__(256) void softmax_rows(
    const bf16_t* __restrict__ S, bf16_t* __restrict__ P, int cols) {
  const long long row = blockIdx.x;
  const bf16x8* inp = (const bf16x8*)(S + row * cols);
  bf16x8* outp      = (bf16x8*)(P + row * cols);
  const int t = threadIdx.x;
  const int w = t >> 6, lane = t & 63;

  const bf16x8 v = inp[t];
  float f[8];
#pragma unroll
  for (int j = 0; j < 8; ++j) f[j] = (float)v[j];

  float m = f[0];
#pragma unroll
  for (int j = 1; j < 8; ++j) m = fmaxf(m, f[j]);
#pragma unroll
  for (int off = 32; off > 0; off >>= 1) m = fmaxf(m, __shfl_xor(m, off));

  __shared__ float red[8];
  if (lane == 0) red[w] = m;
  __syncthreads();
  m = fmaxf(fmaxf(red[0], red[1]), fmaxf(red[2], red[3]));

  float e[8], sum = 0.f;
#pragma unroll
  for (int j = 0; j < 8; ++j) { e[j] = __expf(f[j] - m); sum += e[j]; }
#pragma unroll
  for (int off = 32; off > 0; off >>= 1) sum += __shfl_xor(sum, off);
  if (lane == 0) red[4 + w] = sum;
  __syncthreads();
  sum = red[4] + red[5] + red[6] + red[7];

  const float inv = 1.f / sum;
  bf16x8 o;
#pragma unroll
  for (int j = 0; j < 8; ++j) o[j] = (bf16_t)(e[j] * inv);
  outp[t] = o;
}

// ---------------------------------------------------------------------------
extern "C" void kernel_launch(void* const* d_in, const int* in_sizes, int n_in,
                              void* d_out, int out_size, void* d_ws, size_t ws_size,
                              hipStream_t stream) {
  const int E = 1024, S = 2048, B = 4;
  const int BS = B * S;  // 8192

  const float* x  = (const float*)d_in[0];
  const float* Wq = (const float*)d_in[1];
  const float* bq = (const float*)d_in[2];
  const float* Wk = (const float*)d_in[3];
  const float* bk = (const float*)d_in[4];
  const float* Wv = (const float*)d_in[5];
  const float* bv = (const float*)d_in[6];
  const float* Wo = (const float*)d_in[7];
  const float* bo = (const float*)d_in[8];
  float* out = (float*)d_out;
  (void)bk;  // algebraically eliminated (softmax shift-invariance)

  char* w = (char*)d_ws;
  const size_t MB = 1ull << 20;
  bf16_t* Wqb  = (bf16_t*)(w + 0 * MB);           // 2 MB  Wq bf16
  bf16_t* Wkb  = Wqb + E * E;                     // 2 MB  Wk bf16
  bf16_t* Wob  = (bf16_t*)(w + 4 * MB);           // 2 MB
  float*  vb   = (float*)(w + 6 * MB);            // 4 KB  v = bq.Wk
  bf16_t* xb   = (bf16_t*)(w + 8 * MB);           // 16 MB [8192,1024]
  bf16_t* QVb  = (bf16_t*)(w + 24 * MB);          // 32 MB [8192,2048] = [G|V]
  bf16_t* WqTb = (bf16_t*)(w + 56 * MB);          // 2 MB
  bf16_t* WkTb = WqTb + E * E;                    // 2 MB
  bf16_t* Wqv  = (bf16_t*)(w + 60 * MB);          // 4 MB [MT(1024); Wv(1024)]
  bf16_t* Wvb  = Wqv + E * E;                     //   (Wv rows of Wqv)
  bf16_t* VTb  = (bf16_t*)(w + 72 * MB);          // 16 MB [B][1024,2048]
  bf16_t* Sb   = (bf16_t*)(w + 88 * MB);          // 32 MB scores
  bf16_t* Pb   = (bf16_t*)(w + 8 * MB);           // 32 MB (xb dead after scores)
  bf16_t* Ob   = (bf16_t*)(w + 40 * MB);          // 16 MB (QVb[4096:] dead)

  // ---- all casts in one dispatch (Wq,Wk -> Wqb/Wkb; Wv -> Wqv rows 1024+;
  //      Wo -> Wob; x -> xb)
  {
    const int totalBlocks = ((4 << 18) + (1 << 21)) / 256;  // 12288
    cast_all<<<totalBlocks, 256, 0, stream>>>(
        (const float4*)Wq, (const float4*)Wk, (const float4*)Wv,
        (const float4*)Wo, (const float4*)x,
        (bf16x4*)Wqb, (bf16x4*)Wkb, (bf16x4*)Wvb, (bf16x4*)Wob, (bf16x4*)xb);
  }

  // ---- WqT, WkT (one batched dispatch, z=2)
  transpose_bf16<<<dim3(E / 32, E / 32, 2), dim3(32, 8), 0, stream>>>(
      Wqb, WqTb, E, E, E, (long long)E * E, (long long)E * E);

  // ---- v = bq . Wk (fp32)
  bias_v<<<4, 256, 0, stream>>>(Wk, bq, vb);

  // ---- MT = Wk^T . Wq : gemm_bt(A=WkT, B=WqT) -> Wqv rows 0..1023
  gemm_bt<bf16_t, 0><<<dim3(E / BN, E / BM, 1), 256, 0, stream>>>(
      WkTb, WqTb, Wqv, nullptr, nullptr, nullptr,
      E, E, E, E, E, E, 1.f, 0, 0, 0);

  // ---- fused [G|V] projection: [8192,2048] = xb . Wqv^T + (v|bv)
  //      (G = x.M + v; v = x.Wv^T + bv). 256 blocks = one dispatch round.
  gemm256_bt<bf16_t, 3><<<dim3(2 * E / 256, BS / 256, 1), 512, 0, stream>>>(
      xb, Wqv, QVb, vb, bv, bv,
      BS, 2 * E, E, E, E, 2 * E, 1.f, 0, 0, 0);

  // ---- V^T per batch: [2048,1024](ld 2048) -> [1024,2048]
  transpose_bf16<<<dim3(E / 32, S / 32, B), dim3(32, 8), 0, stream>>>(
      QVb + E, VTb, S, E, 2 * E, (long long)S * 2 * E, (long long)E * S);

  // ---- scores' = G . x^T * E^-0.5 per batch (== scores up to row-consts,
  //      exact under softmax)
  gemm256_bt<bf16_t, 0><<<dim3(S / 256, S / 256, B), 512, 0, stream>>>(
      QVb, xb, Sb, nullptr, nullptr, nullptr,
      S, S, E, 2 * E, E, S, 0.03125f,
      (long long)S * 2 * E, (long long)S * E, (long long)S * S);

  // ---- softmax
  softmax_rows<<<BS, 256, 0, stream>>>(Sb, Pb, S);

  // ---- O = P . (V^T)^T per batch
  gemm_bt<bf16_t, 0><<<dim3(E / BN, S / BM, B), 256, 0, stream>>>(
      Pb, VTb, Ob, nullptr, nullptr, nullptr,
      S, E, S, S, S, E, 1.f,
      (long long)S * S, (long long)E * S, (long long)S * E);

  // ---- y = O . Wo^T + bo
  gemm_bt<float, 1><<<dim3(E / BN, BS / BM, 1), 256, 0, stream>>>(
      Ob, Wob, out, bo, nullptr, nullptr,
      BS, E, E, E, E, E, 1.f, 0, 0, 0);
}

// Round 8
// 285.579 us; speedup vs baseline: 1.3167x; 1.3167x over previous
//
#include <hip/hip_runtime.h>
#include <hip/hip_bf16.h>

// ---------------------------------------------------------------------------
// SelfAttentionHybrid: single-head attention, B=4 S=2048 E=1024, fp32 in/out.
// R14 = R13 with bias_v fixed. R13's algebra verified (absmax unchanged,
// passed) but bias_v ran on FOUR blocks (91.5us, 23 GB/s, 0.29% HBM --
// serial latency loop on 4 CUs). Replaced with wave-parallel dot on WkT:
// one wave per output column, lane reads 16 contiguous bf16, shuffle-reduce.
// 256 blocks, ~4MB coalesced -> ~2.5us.
//
// Algebra (R13, verified): softmax is shift-invariant per row, so
//   S = q.k^T == x.M.x^T + v.x^T (+row-const), M = Wq^T.Wk, v = bq.Wk.
// Fused projection computes [G|V] (N=2048, 256 blocks = ONE dispatch round),
// G = x.M + v; scores = gemm_bt(G, xb) * E^-0.5.
// ---------------------------------------------------------------------------

typedef __bf16 bf16_t;
typedef __bf16 bf16x8 __attribute__((ext_vector_type(8)));
typedef __bf16 bf16x4 __attribute__((ext_vector_type(4)));
typedef float  f32x16 __attribute__((ext_vector_type(16)));
typedef float  f32x4  __attribute__((ext_vector_type(4)));

__device__ __forceinline__ void async_copy16(const void* g, void* l) {
  __builtin_amdgcn_global_load_lds(
      (const __attribute__((address_space(1))) void*)g,
      (__attribute__((address_space(3))) void*)l, 16, 0, 0);
}

// raw workgroup barrier: NO vmcnt/lgkmcnt drain (unlike __syncthreads).
__device__ __forceinline__ void wg_barrier() {
  asm volatile("" ::: "memory");
  __builtin_amdgcn_s_barrier();
  asm volatile("" ::: "memory");
}

// counted LDS wait + rule-18 scheduler pin (MFMAs must not hoist above it)
#define LGKM(n)                                                  \
  do {                                                           \
    asm volatile("s_waitcnt lgkmcnt(" #n ")" ::: "memory");      \
    __builtin_amdgcn_sched_barrier(0);                           \
  } while (0)

#define VM(n) asm volatile("s_waitcnt vmcnt(" #n ")" ::: "memory")

// 32-bit LDS byte address (for asm ds_read; invisible to alias analysis)
__device__ __forceinline__ unsigned lds_addr(const void* p) {
  return (unsigned)(unsigned long long)(__attribute__((address_space(3))) const void*)p;
}

// inline-asm LDS read: compiler cannot see this as an LDS access, so it does
// NOT insert vmcnt(0) ordering vs in-flight global_load_lds prefetches.
// Ordering enforced manually via LGKM() + the per-tile vmcnt/barrier.
__device__ __forceinline__ bf16x8 ds_read128(const bf16_t* p) {
  bf16x8 r;
  asm volatile("ds_read_b128 %0, %1" : "=v"(r) : "v"(lds_addr(p)));
  return r;
}

__device__ __forceinline__ f32x4 mfma16(bf16x8 a, bf16x8 b, f32x4 c) {
  return __builtin_amdgcn_mfma_f32_16x16x32_bf16(a, b, c, 0, 0, 0);
}

__device__ __forceinline__ void store_out(float* p, float v)  { *p = v; }
__device__ __forceinline__ void store_out(bf16_t* p, float v) { *p = (bf16_t)v; }

#define BM 128
#define BN 128
#define BKT 64

// 4 MFMA: a[i] x bb -> acc[ro+i][co..co+1], both k-slices
#define G_AQ(i, ro, bb, co)                                                   \
  acc[(ro) + (i)][(co) + 0] = mfma16(a[i][0], bb[0][0], acc[(ro) + (i)][(co) + 0]); \
  acc[(ro) + (i)][(co) + 1] = mfma16(a[i][0], bb[1][0], acc[(ro) + (i)][(co) + 1]); \
  acc[(ro) + (i)][(co) + 0] = mfma16(a[i][1], bb[0][1], acc[(ro) + (i)][(co) + 0]); \
  acc[(ro) + (i)][(co) + 1] = mfma16(a[i][1], bb[1][1], acc[(ro) + (i)][(co) + 1]);

// 8 MFMA: all a[i] x bb[j] -> acc[0..3][co+j], both k-slices
#define G_BQ(j, bb, co)                                              \
  acc[0][(co) + (j)] = mfma16(a[0][0], bb[j][0], acc[0][(co) + (j)]); \
  acc[1][(co) + (j)] = mfma16(a[1][0], bb[j][0], acc[1][(co) + (j)]); \
  acc[2][(co) + (j)] = mfma16(a[2][0], bb[j][0], acc[2][(co) + (j)]); \
  acc[3][(co) + (j)] = mfma16(a[3][0], bb[j][0], acc[3][(co) + (j)]); \
  acc[0][(co) + (j)] = mfma16(a[0][1], bb[j][1], acc[0][(co) + (j)]); \
  acc[1][(co) + (j)] = mfma16(a[1][1], bb[j][1], acc[1][(co) + (j)]); \
  acc[2][(co) + (j)] = mfma16(a[2][1], bb[j][1], acc[2][(co) + (j)]); \
  acc[3][(co) + (j)] = mfma16(a[3][1], bb[j][1], acc[3][(co) + (j)]);

// ---------------------------------------------------------------------------
// gemm256_bt (R10 config): C[M,N] = A[M,K](lda) x B[N,K](ldb)^T * scale + b.
// 512 thr = 8 waves (2Mx4N); wave tile 128x64 = 8x4 frags of 16x16x32 MFMA.
// LDS [2 buf][256 rows][64 bf16] per matrix; slot (r,cc) holds global chunk
// cc^(r&7); reads use slot kc^(r&7) (involution; 16-row instrs => 2-way max,
// measured 0 conflicts).
// Requires M%256==0, N%256==0, K%128==0 (NT even), gridDim.y%8==0.
// ---------------------------------------------------------------------------
template <typename OutT, int NBIAS>
__global__ __launch_bounds__(512, 2) void gemm256_bt(
    const bf16_t* __restrict__ A, const bf16_t* __restrict__ B,
    OutT* __restrict__ C,
    const float* __restrict__ b0, const float* __restrict__ b1,
    const float* __restrict__ b2,
    int M, int N, int K, int lda, int ldb, int ldc, float scale,
    long long strideA, long long strideB, long long strideC) {
  const int z = blockIdx.z;
  A += (long long)z * strideA;
  B += (long long)z * strideB;
  C += (long long)z * strideC;

  // L2 supertile remap: 8 y-tiles per supertile, y-fastest inside.
  int bx = blockIdx.x, by = blockIdx.y;
  {
    const int GX  = gridDim.x;
    const int id  = by * GX + bx;
    const int per = GX * 8;
    const int grp = id / per;
    const int rem = id - grp * per;
    by = grp * 8 + (rem & 7);
    bx = rem >> 3;
  }

  __shared__ __align__(16) bf16_t As[2 * 256 * 64];  // 64 KB
  __shared__ __align__(16) bf16_t Bs[2 * 256 * 64];  // 64 KB

  const int t    = threadIdx.x;
  const int lane = t & 63;
  const int w    = t >> 6;
  const int wm   = w & 1;    // M-half of output tile
  const int wn   = w >> 1;   // N-quarter of output tile
  const int g    = lane >> 4;
  const int l7   = lane & 7;
  const int r15  = lane & 15;
  const int tileM = by * 256;
  const int tileN = bx * 256;

  // staging constants: thread covers chunks t and t+512 of each half-tile
  const int row0 = t >> 3;                    // 0..63
  const int gcc  = (t & 7) ^ (row0 & 7);      // swizzled source chunk
  const int dstb = (t & ~63) * 8;             // wave-uniform LDS base (elems)

  // read constants
  const int sw0 = ((0 + g) ^ l7) * 8;         // k-slice 0 chunk offset (elems)
  const int sw1 = ((4 + g) ^ l7) * 8;         // k-slice 1
  const int aRow = (wm * 128 + r15) * 64;
  const int bRow = (wn * 64 + r15) * 64;

  const int NT = K >> 6;

  f32x4 acc[8][4] = {};

  auto stageA = [&](int kt, int h) {
    const int cb = (kt & 1) * 16384;
    const bf16_t* src =
        A + (long long)(tileM + h * 128 + row0) * lda + kt * 64 + gcc * 8;
    bf16_t* dst = &As[cb + h * 8192 + dstb];
    async_copy16(src, dst);
    async_copy16(src + (long long)64 * lda, dst + 4096);
  };
  auto stageB = [&](int kt, int h) {
    const int cb = (kt & 1) * 16384;
    const bf16_t* src =
        B + (long long)(tileN + h * 128 + row0) * ldb + kt * 64 + gcc * 8;
    bf16_t* dst = &Bs[cb + h * 8192 + dstb];
    async_copy16(src, dst);
    async_copy16(src + (long long)64 * ldb, dst + 4096);
  };

  // prologue: stage tile 0 only; retire; pre-read B0(0) (4 reads stay
  // outstanding into tile 0 ph0 -- steady-state invariant).
  stageA(0, 0); stageA(0, 1); stageB(0, 0); stageB(0, 1);
  VM(0);
  wg_barrier();

  bf16x8 a[4][2], P[2][2], Q[2][2];
#pragma unroll
  for (int j = 0; j < 2; ++j) {
    P[j][0] = ds_read128(&Bs[bRow + j * 1024 + sw0]);
    P[j][1] = ds_read128(&Bs[bRow + j * 1024 + sw1]);
  }

  // bc = B0(kt) (read at prev ph3); bq = scratch: gets B1(kt) then B0(kt+1)
  auto tile_step = [&](int kt, bf16x8 (&bc)[2][2], bf16x8 (&bq)[2][2]) {
    const int cb = (kt & 1) * 16384;
    const int kn = kt + 1;
    const bf16_t* Ab = &As[cb + aRow];
    const bf16_t* Bb = &Bs[cb + bRow];

    // ---- ph0: issue A0 reads (outstanding 4+8=12); stage B(kt+1);
    //           MFMA M0N0 interleaved on counted lgkm.
#pragma unroll
    for (int i = 0; i < 4; ++i) {
      a[i][0] = ds_read128(Ab + i * 1024 + sw0);
      a[i][1] = ds_read128(Ab + i * 1024 + sw1);
    }
    if (kn < NT) { stageB(kn, 0); stageB(kn, 1); }
    __builtin_amdgcn_s_setprio(1);
    LGKM(6);  // retires B0(kt) x4 + a[0] pair
    G_AQ(0, 0, bc, 0)
    LGKM(4);
    G_AQ(1, 0, bc, 0)
    LGKM(2);
    G_AQ(2, 0, bc, 0)
    LGKM(0);
    G_AQ(3, 0, bc, 0)
    __builtin_amdgcn_s_setprio(0);

    // ---- ph1: issue B1 reads (4); stage A(kt+1); MFMA M0N1 interleaved.
#pragma unroll
    for (int j = 0; j < 2; ++j) {
      bq[j][0] = ds_read128(Bb + 2048 + j * 1024 + sw0);
      bq[j][1] = ds_read128(Bb + 2048 + j * 1024 + sw1);
    }
    if (kn < NT) { stageA(kn, 0); stageA(kn, 1); }
    __builtin_amdgcn_s_setprio(1);
    LGKM(2);  // bq[0] ready
    G_BQ(0, bq, 2)
    LGKM(0);  // bq[1] ready
    G_BQ(1, bq, 2)
    __builtin_amdgcn_s_setprio(0);

    // ---- ph2: issue A1 reads (8); MFMA M1N1 interleaved; then retire
    //           staging(kt+1) [exact: only those 8 in flight] + barrier.
#pragma unroll
    for (int i = 0; i < 4; ++i) {
      a[i][0] = ds_read128(Ab + 4096 + i * 1024 + sw0);
      a[i][1] = ds_read128(Ab + 4096 + i * 1024 + sw1);
    }
    __builtin_amdgcn_s_setprio(1);
    LGKM(6);
    G_AQ(0, 4, bq, 2)
    LGKM(4);
    G_AQ(1, 4, bq, 2)
    LGKM(2);
    G_AQ(2, 4, bq, 2)
    LGKM(0);
    G_AQ(3, 4, bq, 2)
    __builtin_amdgcn_s_setprio(0);
    VM(0);
    wg_barrier();  // buffer (kt+1)&1 now visible to all waves

    // ---- ph3: read B0(kt+1) -> bq (B1 dead; drains under next ph0's
    //           LGKM(6)); MFMA M1N0 -- all inputs resident, no wait.
    if (kn < NT) {
      const bf16_t* Bn = &Bs[(kn & 1) * 16384 + bRow];
#pragma unroll
      for (int j = 0; j < 2; ++j) {
        bq[j][0] = ds_read128(Bn + j * 1024 + sw0);
        bq[j][1] = ds_read128(Bn + j * 1024 + sw1);
      }
    }
    __builtin_amdgcn_s_setprio(1);
    G_AQ(0, 4, bc, 0)
    G_AQ(1, 4, bc, 0)
    G_AQ(2, 4, bc, 0)
    G_AQ(3, 4, bc, 0)
    __builtin_amdgcn_s_setprio(0);
  };

  for (int kt = 0; kt < NT; kt += 2) {
    tile_step(kt,     P, Q);   // bc = P holds B0(kt);   Q gets B1, B0(kt+1)
    tile_step(kt + 1, Q, P);   // bc = Q holds B0(kt+1); P gets B1, B0(kt+2)
  }

  // epilogue: 16x16 C map: col = lane&15, row = (lane>>4)*4 + r.
  // j innermost: 4 consecutive 32B segments per row -> 128B write-combining.
  float bvv[4];
#pragma unroll
  for (int j = 0; j < 4; ++j) {
    const int col = tileN + wn * 64 + j * 16 + r15;
    float bv = 0.f;
    if (NBIAS == 1) bv = b0[col];
    if (NBIAS == 3) {
      const float* bp = col < 1024 ? b0 : (col < 2048 ? b1 : b2);
      bv = bp[col & 1023];
    }
    bvv[j] = bv;
  }
#pragma unroll
  for (int i = 0; i < 8; ++i) {
#pragma unroll
    for (int r = 0; r < 4; ++r) {
      const long long row = tileM + wm * 128 + i * 16 + g * 4 + r;
      OutT* Crow = C + row * ldc + tileN + wn * 64 + r15;
#pragma unroll
      for (int j = 0; j < 4; ++j)
        store_out(Crow + j * 16, acc[i][j][r] * scale + bvv[j]);
    }
  }
}

// ---------------------------------------------------------------------------
// 128^2 kernel — PV, out-proj, and the small MT = Wk^T.Wq precompute.
// ---------------------------------------------------------------------------
template <typename OutT, int NBIAS>
__global__ __launch_bounds__(256) void gemm_bt(
    const bf16_t* __restrict__ A, const bf16_t* __restrict__ B,
    OutT* __restrict__ C,
    const float* __restrict__ b0, const float* __restrict__ b1,
    const float* __restrict__ b2,
    int M, int N, int K, int lda, int ldb, int ldc, float scale,
    long long strideA, long long strideB, long long strideC) {
  const int z = blockIdx.z;
  A += (long long)z * strideA;
  B += (long long)z * strideB;
  C += (long long)z * strideC;

  int bx = blockIdx.x, by = blockIdx.y;
  {
    const int GX  = gridDim.x;
    const int id  = by * GX + bx;
    const int per = GX * 8;
    const int grp = id / per;
    const int rem = id - grp * per;
    by = grp * 8 + (rem & 7);
    bx = rem >> 3;
  }

  __shared__ __align__(16) bf16_t As[BM * BKT];  // 16 KB
  __shared__ __align__(16) bf16_t Bs[BN * BKT];  // 16 KB

  const int t    = threadIdx.x;
  const int lane = t & 63;
  const int w    = t >> 6;
  const int wm   = w & 1;
  const int wn   = w >> 1;
  const int tileM = by * BM;
  const int tileN = bx * BN;

  f32x16 acc[2][2] = {};

  for (int k0 = 0; k0 < K; k0 += BKT) {
#pragma unroll
    for (int i = 0; i < 4; ++i) {
      const int c   = t + 256 * i;
      const int row = c >> 3;
      const int cc  = c & 7;
      const int gcc = cc ^ (row & 7);
      const int ldsbase = ((t & ~63) + 256 * i) * 8;
      async_copy16(A + (long long)(tileM + row) * lda + k0 + gcc * 8, &As[ldsbase]);
      async_copy16(B + (long long)(tileN + row) * ldb + k0 + gcc * 8, &Bs[ldsbase]);
    }
    __syncthreads();

#pragma unroll
    for (int s = 0; s < 4; ++s) {
      const int kc = s + 4 * (lane >> 5);
      bf16x8 af[2], bfr[2];
#pragma unroll
      for (int ti = 0; ti < 2; ++ti) {
        const int row = wm * 64 + ti * 32 + (lane & 31);
        af[ti] = *(const bf16x8*)&As[row * BKT + ((kc ^ (row & 7)) * 8)];
      }
#pragma unroll
      for (int tj = 0; tj < 2; ++tj) {
        const int row = wn * 64 + tj * 32 + (lane & 31);
        bfr[tj] = *(const bf16x8*)&Bs[row * BKT + ((kc ^ (row & 7)) * 8)];
      }
#pragma unroll
      for (int ti = 0; ti < 2; ++ti)
#pragma unroll
        for (int tj = 0; tj < 2; ++tj)
          acc[ti][tj] = __builtin_amdgcn_mfma_f32_32x32x16_bf16(
              af[ti], bfr[tj], acc[ti][tj], 0, 0, 0);
    }
    __syncthreads();
  }

#pragma unroll
  for (int tj = 0; tj < 2; ++tj) {
    const int col = tileN + wn * 64 + tj * 32 + (lane & 31);
    float bv = 0.f;
    if (NBIAS == 1) bv = b0[col];
    if (NBIAS == 3) {
      const float* bp = col < 1024 ? b0 : (col < 2048 ? b1 : b2);
      bv = bp[col & 1023];
    }
#pragma unroll
    for (int ti = 0; ti < 2; ++ti) {
      const int rowb = tileM + wm * 64 + ti * 32 + 4 * (lane >> 5);
#pragma unroll
      for (int r = 0; r < 16; ++r) {
        const int row = rowb + (r & 3) + 8 * (r >> 2);
        store_out(&C[(long long)row * ldc + col], acc[ti][tj][r] * scale + bv);
      }
    }
  }
}

// ---------------------------------------------------------------------------
// fused cast: 4 weights (separate dsts) + x in one dispatch.
// ---------------------------------------------------------------------------
__global__ __launch_bounds__(256) void cast_all(
    const float4* __restrict__ w0, const float4* __restrict__ w1,
    const float4* __restrict__ w2, const float4* __restrict__ w3,
    const float4* __restrict__ x,
    bf16x4* __restrict__ d0, bf16x4* __restrict__ d1,
    bf16x4* __restrict__ d2, bf16x4* __restrict__ d3,
    bf16x4* __restrict__ xdst) {
  const int N4W = 1 << 18;  // 1024*1024/4
  const int id = blockIdx.x * 256 + threadIdx.x;
  const float4* src;
  bf16x4* dst;
  if (id < 4 * N4W) {
    const int z = id >> 18;
    const int i = id & (N4W - 1);
    src = (z == 0 ? w0 : z == 1 ? w1 : z == 2 ? w2 : w3) + i;
    dst = (z == 0 ? d0 : z == 1 ? d1 : z == 2 ? d2 : d3) + i;
  } else {
    const int i = id - 4 * N4W;
    src = x + i;
    dst = xdst + i;
  }
  const float4 v = *src;
  bf16x4 o;
  o[0] = (bf16_t)v.x; o[1] = (bf16_t)v.y; o[2] = (bf16_t)v.z; o[3] = (bf16_t)v.w;
  *dst = o;
}

// ---------------------------------------------------------------------------
// v = bq . Wk via WkT rows: one WAVE per output column j (grid 256 x 4
// waves); lane reads 16 contiguous bf16 of WkT row j, FMA vs fp32 bq,
// 64-lane shuffle reduce. Fully coalesced; replaces R13's 4-block serial
// loop (91.5us -> ~2.5us).
// ---------------------------------------------------------------------------
__global__ __launch_bounds__(256) void bias_v(
    const bf16_t* __restrict__ WkT, const float* __restrict__ bq,
    float* __restrict__ v) {
  const int wv   = threadIdx.x >> 6;
  const int lane = threadIdx.x & 63;
  const int j    = blockIdx.x * 4 + wv;  // grid 256 -> j in [0,1024)
  const bf16x8* row = (const bf16x8*)(WkT + (long long)j * 1024);
  float acc = 0.f;
#pragma unroll
  for (int h = 0; h < 2; ++h) {
    const bf16x8 w8 = row[lane * 2 + h];
#pragma unroll
    for (int e = 0; e < 8; ++e)
      acc += (float)w8[e] * bq[lane * 16 + h * 8 + e];
  }
#pragma unroll
  for (int off = 32; off > 0; off >>= 1) acc += __shfl_xor(acc, off);
  if (lane == 0) v[j] = acc;
}

// ---------------------------------------------------------------------------
// bf16 transpose [R,C](ldin) -> [C,R], batched via blockIdx.z
// ---------------------------------------------------------------------------
__global__ __launch_bounds__(256) void transpose_bf16(
    const bf16_t* __restrict__ in, bf16_t* __restrict__ out, int R, int C,
    int ldin, long long sIn, long long sOut) {
  in  += (long long)blockIdx.z * sIn;
  out += (long long)blockIdx.z * sOut;
  __shared__ bf16_t tile[32][33];
  const int tx = threadIdx.x, ty = threadIdx.y;
  const int x = blockIdx.x * 32 + tx;
  const int y0 = blockIdx.y * 32;
#pragma unroll
  for (int j = 0; j < 32; j += 8)
    tile[ty + j][tx] = in[(long long)(y0 + ty + j) * ldin + x];
  __syncthreads();
  const int x2 = y0 + tx;
  const int y2 = blockIdx.x * 32;
#pragma unroll
  for (int j = 0; j < 32; j += 8)
    out[(long long)(y2 + ty + j) * R + x2] = tile[tx][ty + j];
}

// ---------------------------------------------------------------------------
// row softmax: 2048-wide rows, 256 threads x 8 elems
// ---------------------------------------------------------------------------
__global__ __launch_bounds__(256) void softmax_rows(
    const bf16_t* __restrict__ S, bf16_t* __restrict__ P, int cols) {
  const long long row = blockIdx.x;
  const bf16x8* inp = (const bf16x8*)(S + row * cols);
  bf16x8* outp      = (bf16x8*)(P + row * cols);
  const int t = threadIdx.x;
  const int w = t >> 6, lane = t & 63;

  const bf16x8 v = inp[t];
  float f[8];
#pragma unroll
  for (int j = 0; j < 8; ++j) f[j] = (float)v[j];

  float m = f[0];
#pragma unroll
  for (int j = 1; j < 8; ++j) m = fmaxf(m, f[j]);
#pragma unroll
  for (int off = 32; off > 0; off >>= 1) m = fmaxf(m, __shfl_xor(m, off));

  __shared__ float red[8];
  if (lane == 0) red[w] = m;
  __syncthreads();
  m = fmaxf(fmaxf(red[0], red[1]), fmaxf(red[2], red[3]));

  float e[8], sum = 0.f;
#pragma unroll
  for (int j = 0; j < 8; ++j) { e[j] = __expf(f[j] - m); sum += e[j]; }
#pragma unroll
  for (int off = 32; off > 0; off >>= 1) sum += __shfl_xor(sum, off);
  if (lane == 0) red[4 + w] = sum;
  __syncthreads();
  sum = red[4] + red[5] + red[6] + red[7];

  const float inv = 1.f / sum;
  bf16x8 o;
#pragma unroll
  for (int j = 0; j < 8; ++j) o[j] = (bf16_t)(e[j] * inv);
  outp[t] = o;
}

// ---------------------------------------------------------------------------
extern "C" void kernel_launch(void* const* d_in, const int* in_sizes, int n_in,
                              void* d_out, int out_size, void* d_ws, size_t ws_size,
                              hipStream_t stream) {
  const int E = 1024, S = 2048, B = 4;
  const int BS = B * S;  // 8192

  const float* x  = (const float*)d_in[0];
  const float* Wq = (const float*)d_in[1];
  const float* bq = (const float*)d_in[2];
  const float* Wk = (const float*)d_in[3];
  const float* bk = (const float*)d_in[4];
  const float* Wv = (const float*)d_in[5];
  const float* bv = (const float*)d_in[6];
  const float* Wo = (const float*)d_in[7];
  const float* bo = (const float*)d_in[8];
  float* out = (float*)d_out;
  (void)bk; (void)Wk;  // bk algebraically eliminated; Wk used via bf16 copy

  char* w = (char*)d_ws;
  const size_t MB = 1ull << 20;
  bf16_t* Wqb  = (bf16_t*)(w + 0 * MB);           // 2 MB  Wq bf16
  bf16_t* Wkb  = Wqb + E * E;                     // 2 MB  Wk bf16
  bf16_t* Wob  = (bf16_t*)(w + 4 * MB);           // 2 MB
  float*  vb   = (float*)(w + 6 * MB);            // 4 KB  v = bq.Wk
  bf16_t* xb   = (bf16_t*)(w + 8 * MB);           // 16 MB [8192,1024]
  bf16_t* QVb  = (bf16_t*)(w + 24 * MB);          // 32 MB [8192,2048] = [G|V]
  bf16_t* WqTb = (bf16_t*)(w + 56 * MB);          // 2 MB
  bf16_t* WkTb = WqTb + E * E;                    // 2 MB
  bf16_t* Wqv  = (bf16_t*)(w + 60 * MB);          // 4 MB [MT(1024); Wv(1024)]
  bf16_t* Wvb  = Wqv + E * E;                     //   (Wv rows of Wqv)
  bf16_t* VTb  = (bf16_t*)(w + 72 * MB);          // 16 MB [B][1024,2048]
  bf16_t* Sb   = (bf16_t*)(w + 88 * MB);          // 32 MB scores
  bf16_t* Pb   = (bf16_t*)(w + 8 * MB);           // 32 MB (xb dead after scores)
  bf16_t* Ob   = (bf16_t*)(w + 40 * MB);          // 16 MB (QVb[4096:] dead)

  // ---- all casts in one dispatch (Wq,Wk -> Wqb/Wkb; Wv -> Wqv rows 1024+;
  //      Wo -> Wob; x -> xb)
  {
    const int totalBlocks = ((4 << 18) + (1 << 21)) / 256;  // 12288
    cast_all<<<totalBlocks, 256, 0, stream>>>(
        (const float4*)Wq, (const float4*)Wk, (const float4*)Wv,
        (const float4*)Wo, (const float4*)x,
        (bf16x4*)Wqb, (bf16x4*)Wkb, (bf16x4*)Wvb, (bf16x4*)Wob, (bf16x4*)xb);
  }

  // ---- WqT, WkT (one batched dispatch, z=2)
  transpose_bf16<<<dim3(E / 32, E / 32, 2), dim3(32, 8), 0, stream>>>(
      Wqb, WqTb, E, E, E, (long long)E * E, (long long)E * E);

  // ---- v = bq . Wk = WkT-row dot bq (wave per column)
  bias_v<<<256, 256, 0, stream>>>(WkTb, bq, vb);

  // ---- MT = Wk^T . Wq : gemm_bt(A=WkT, B=WqT) -> Wqv rows 0..1023
  gemm_bt<bf16_t, 0><<<dim3(E / BN, E / BM, 1), 256, 0, stream>>>(
      WkTb, WqTb, Wqv, nullptr, nullptr, nullptr,
      E, E, E, E, E, E, 1.f, 0, 0, 0);

  // ---- fused [G|V] projection: [8192,2048] = xb . Wqv^T + (v|bv)
  //      (G = x.M + v; V = x.Wv^T + bv). 256 blocks = one dispatch round.
  gemm256_bt<bf16_t, 3><<<dim3(2 * E / 256, BS / 256, 1), 512, 0, stream>>>(
      xb, Wqv, QVb, vb, bv, bv,
      BS, 2 * E, E, E, E, 2 * E, 1.f, 0, 0, 0);

  // ---- V^T per batch: [2048,1024](ld 2048) -> [1024,2048]
  transpose_bf16<<<dim3(E / 32, S / 32, B), dim3(32, 8), 0, stream>>>(
      QVb + E, VTb, S, E, 2 * E, (long long)S * 2 * E, (long long)E * S);

  // ---- scores' = G . x^T * E^-0.5 per batch (== scores up to row-consts,
  //      exact under softmax)
  gemm256_bt<bf16_t, 0><<<dim3(S / 256, S / 256, B), 512, 0, stream>>>(
      QVb, xb, Sb, nullptr, nullptr, nullptr,
      S, S, E, 2 * E, E, S, 0.03125f,
      (long long)S * 2 * E, (long long)S * E, (long long)S * S);

  // ---- softmax
  softmax_rows<<<BS, 256, 0, stream>>>(Sb, Pb, S);

  // ---- O = P . (V^T)^T per batch
  gemm_bt<bf16_t, 0><<<dim3(E / BN, S / BM, B), 256, 0, stream>>>(
      Pb, VTb, Ob, nullptr, nullptr, nullptr,
      S, E, S, S, S, E, 1.f,
      (long long)S * S, (long long)E * S, (long long)S * E);

  // ---- y = O . Wo^T + bo
  gemm_bt<float, 1><<<dim3(E / BN, BS / BM, 1), 256, 0, stream>>>(
      Ob, Wob, out, bo, nullptr, nullptr,
      BS, E, E, E, E, E, 1.f, 0, 0, 0);
}

// Round 9
// 281.720 us; speedup vs baseline: 1.3347x; 1.0137x over previous
//
#include <hip/hip_runtime.h>
#include <hip/hip_bf16.h>

// ---------------------------------------------------------------------------
// SelfAttentionHybrid: single-head attention, B=4 S=2048 E=1024, fp32 in/out.
// R15: PV + out-proj move off the 128^2 kernel (45.8us PV, 4.19M bank
// conflicts = structural 4-way from 32x32 frags; LDS reads were 60% of
// wall). New gemm128n_bt: 256Mx128N tile, 8 waves 4Mx2N (wave tile 64x64 =
// 4x4 16x16 frags, conflict-free 16-row reads), R10's proven schedule:
// 1 barrier/tile + counted-lgkm ladder + exact VM(0) + P/Q B-reg ping-pong.
// Grids: PV (8,8,4)=256 blocks, out-proj (8,32)=256 blocks -- one full
// round each (the 128^2 versions ran 512 blocks = 2 rounds).
// QV-projection + scores keep gemm256_bt; MT precompute keeps gemm_bt.
//
// Algebra (R13, verified): softmax shift-invariance =>
//   S = q.k^T == x.M.x^T + v.x^T (+row-const), M = Wq^T.Wk, v = bq.Wk.
// ---------------------------------------------------------------------------

typedef __bf16 bf16_t;
typedef __bf16 bf16x8 __attribute__((ext_vector_type(8)));
typedef __bf16 bf16x4 __attribute__((ext_vector_type(4)));
typedef float  f32x16 __attribute__((ext_vector_type(16)));
typedef float  f32x4  __attribute__((ext_vector_type(4)));

__device__ __forceinline__ void async_copy16(const void* g, void* l) {
  __builtin_amdgcn_global_load_lds(
      (const __attribute__((address_space(1))) void*)g,
      (__attribute__((address_space(3))) void*)l, 16, 0, 0);
}

// raw workgroup barrier: NO vmcnt/lgkmcnt drain (unlike __syncthreads).
__device__ __forceinline__ void wg_barrier() {
  asm volatile("" ::: "memory");
  __builtin_amdgcn_s_barrier();
  asm volatile("" ::: "memory");
}

// counted LDS wait + rule-18 scheduler pin (MFMAs must not hoist above it)
#define LGKM(n)                                                  \
  do {                                                           \
    asm volatile("s_waitcnt lgkmcnt(" #n ")" ::: "memory");      \
    __builtin_amdgcn_sched_barrier(0);                           \
  } while (0)

#define VM(n) asm volatile("s_waitcnt vmcnt(" #n ")" ::: "memory")

// 32-bit LDS byte address (for asm ds_read; invisible to alias analysis)
__device__ __forceinline__ unsigned lds_addr(const void* p) {
  return (unsigned)(unsigned long long)(__attribute__((address_space(3))) const void*)p;
}

// inline-asm LDS read: compiler cannot see this as an LDS access, so it does
// NOT insert vmcnt(0) ordering vs in-flight global_load_lds prefetches.
// Ordering enforced manually via LGKM() + the per-tile vmcnt/barrier.
__device__ __forceinline__ bf16x8 ds_read128(const bf16_t* p) {
  bf16x8 r;
  asm volatile("ds_read_b128 %0, %1" : "=v"(r) : "v"(lds_addr(p)));
  return r;
}

__device__ __forceinline__ f32x4 mfma16(bf16x8 a, bf16x8 b, f32x4 c) {
  return __builtin_amdgcn_mfma_f32_16x16x32_bf16(a, b, c, 0, 0, 0);
}

__device__ __forceinline__ void store_out(float* p, float v)  { *p = v; }
__device__ __forceinline__ void store_out(bf16_t* p, float v) { *p = (bf16_t)v; }

#define BM 128
#define BN 128
#define BKT 64

// 4 MFMA: a[i] x bb -> acc[ro+i][co..co+1], both k-slices
#define G_AQ(i, ro, bb, co)                                                   \
  acc[(ro) + (i)][(co) + 0] = mfma16(a[i][0], bb[0][0], acc[(ro) + (i)][(co) + 0]); \
  acc[(ro) + (i)][(co) + 1] = mfma16(a[i][0], bb[1][0], acc[(ro) + (i)][(co) + 1]); \
  acc[(ro) + (i)][(co) + 0] = mfma16(a[i][1], bb[0][1], acc[(ro) + (i)][(co) + 0]); \
  acc[(ro) + (i)][(co) + 1] = mfma16(a[i][1], bb[1][1], acc[(ro) + (i)][(co) + 1]);

// 8 MFMA: all a[i] x bb[j] -> acc[0..3][co+j], both k-slices
#define G_BQ(j, bb, co)                                              \
  acc[0][(co) + (j)] = mfma16(a[0][0], bb[j][0], acc[0][(co) + (j)]); \
  acc[1][(co) + (j)] = mfma16(a[1][0], bb[j][0], acc[1][(co) + (j)]); \
  acc[2][(co) + (j)] = mfma16(a[2][0], bb[j][0], acc[2][(co) + (j)]); \
  acc[3][(co) + (j)] = mfma16(a[3][0], bb[j][0], acc[3][(co) + (j)]); \
  acc[0][(co) + (j)] = mfma16(a[0][1], bb[j][1], acc[0][(co) + (j)]); \
  acc[1][(co) + (j)] = mfma16(a[1][1], bb[j][1], acc[1][(co) + (j)]); \
  acc[2][(co) + (j)] = mfma16(a[2][1], bb[j][1], acc[2][(co) + (j)]); \
  acc[3][(co) + (j)] = mfma16(a[3][1], bb[j][1], acc[3][(co) + (j)]);

// ---------------------------------------------------------------------------
// gemm256_bt (R10 config): C[M,N] = A[M,K](lda) x B[N,K](ldb)^T * scale + b.
// 512 thr = 8 waves (2Mx4N); wave tile 128x64 = 8x4 frags of 16x16x32 MFMA.
// LDS [2 buf][256 rows][64 bf16] per matrix; slot (r,cc) holds global chunk
// cc^(r&7); reads use slot kc^(r&7) (involution; 16-row instrs => 2-way max,
// measured 0 conflicts).
// Requires M%256==0, N%256==0, K%128==0 (NT even), gridDim.y%8==0.
// ---------------------------------------------------------------------------
template <typename OutT, int NBIAS>
__global__ __launch_bounds__(512, 2) void gemm256_bt(
    const bf16_t* __restrict__ A, const bf16_t* __restrict__ B,
    OutT* __restrict__ C,
    const float* __restrict__ b0, const float* __restrict__ b1,
    const float* __restrict__ b2,
    int M, int N, int K, int lda, int ldb, int ldc, float scale,
    long long strideA, long long strideB, long long strideC) {
  const int z = blockIdx.z;
  A += (long long)z * strideA;
  B += (long long)z * strideB;
  C += (long long)z * strideC;

  // L2 supertile remap: 8 y-tiles per supertile, y-fastest inside.
  int bx = blockIdx.x, by = blockIdx.y;
  {
    const int GX  = gridDim.x;
    const int id  = by * GX + bx;
    const int per = GX * 8;
    const int grp = id / per;
    const int rem = id - grp * per;
    by = grp * 8 + (rem & 7);
    bx = rem >> 3;
  }

  __shared__ __align__(16) bf16_t As[2 * 256 * 64];  // 64 KB
  __shared__ __align__(16) bf16_t Bs[2 * 256 * 64];  // 64 KB

  const int t    = threadIdx.x;
  const int lane = t & 63;
  const int w    = t >> 6;
  const int wm   = w & 1;    // M-half of output tile
  const int wn   = w >> 1;   // N-quarter of output tile
  const int g    = lane >> 4;
  const int l7   = lane & 7;
  const int r15  = lane & 15;
  const int tileM = by * 256;
  const int tileN = bx * 256;

  // staging constants: thread covers chunks t and t+512 of each half-tile
  const int row0 = t >> 3;                    // 0..63
  const int gcc  = (t & 7) ^ (row0 & 7);      // swizzled source chunk
  const int dstb = (t & ~63) * 8;             // wave-uniform LDS base (elems)

  // read constants
  const int sw0 = ((0 + g) ^ l7) * 8;         // k-slice 0 chunk offset (elems)
  const int sw1 = ((4 + g) ^ l7) * 8;         // k-slice 1
  const int aRow = (wm * 128 + r15) * 64;
  const int bRow = (wn * 64 + r15) * 64;

  const int NT = K >> 6;

  f32x4 acc[8][4] = {};

  auto stageA = [&](int kt, int h) {
    const int cb = (kt & 1) * 16384;
    const bf16_t* src =
        A + (long long)(tileM + h * 128 + row0) * lda + kt * 64 + gcc * 8;
    bf16_t* dst = &As[cb + h * 8192 + dstb];
    async_copy16(src, dst);
    async_copy16(src + (long long)64 * lda, dst + 4096);
  };
  auto stageB = [&](int kt, int h) {
    const int cb = (kt & 1) * 16384;
    const bf16_t* src =
        B + (long long)(tileN + h * 128 + row0) * ldb + kt * 64 + gcc * 8;
    bf16_t* dst = &Bs[cb + h * 8192 + dstb];
    async_copy16(src, dst);
    async_copy16(src + (long long)64 * ldb, dst + 4096);
  };

  // prologue: stage tile 0 only; retire; pre-read B0(0) (4 reads stay
  // outstanding into tile 0 ph0 -- steady-state invariant).
  stageA(0, 0); stageA(0, 1); stageB(0, 0); stageB(0, 1);
  VM(0);
  wg_barrier();

  bf16x8 a[4][2], P[2][2], Q[2][2];
#pragma unroll
  for (int j = 0; j < 2; ++j) {
    P[j][0] = ds_read128(&Bs[bRow + j * 1024 + sw0]);
    P[j][1] = ds_read128(&Bs[bRow + j * 1024 + sw1]);
  }

  // bc = B0(kt) (read at prev ph3); bq = scratch: gets B1(kt) then B0(kt+1)
  auto tile_step = [&](int kt, bf16x8 (&bc)[2][2], bf16x8 (&bq)[2][2]) {
    const int cb = (kt & 1) * 16384;
    const int kn = kt + 1;
    const bf16_t* Ab = &As[cb + aRow];
    const bf16_t* Bb = &Bs[cb + bRow];

    // ---- ph0: issue A0 reads (outstanding 4+8=12); stage B(kt+1);
    //           MFMA M0N0 interleaved on counted lgkm.
#pragma unroll
    for (int i = 0; i < 4; ++i) {
      a[i][0] = ds_read128(Ab + i * 1024 + sw0);
      a[i][1] = ds_read128(Ab + i * 1024 + sw1);
    }
    if (kn < NT) { stageB(kn, 0); stageB(kn, 1); }
    __builtin_amdgcn_s_setprio(1);
    LGKM(6);  // retires B0(kt) x4 + a[0] pair
    G_AQ(0, 0, bc, 0)
    LGKM(4);
    G_AQ(1, 0, bc, 0)
    LGKM(2);
    G_AQ(2, 0, bc, 0)
    LGKM(0);
    G_AQ(3, 0, bc, 0)
    __builtin_amdgcn_s_setprio(0);

    // ---- ph1: issue B1 reads (4); stage A(kt+1); MFMA M0N1 interleaved.
#pragma unroll
    for (int j = 0; j < 2; ++j) {
      bq[j][0] = ds_read128(Bb + 2048 + j * 1024 + sw0);
      bq[j][1] = ds_read128(Bb + 2048 + j * 1024 + sw1);
    }
    if (kn < NT) { stageA(kn, 0); stageA(kn, 1); }
    __builtin_amdgcn_s_setprio(1);
    LGKM(2);  // bq[0] ready
    G_BQ(0, bq, 2)
    LGKM(0);  // bq[1] ready
    G_BQ(1, bq, 2)
    __builtin_amdgcn_s_setprio(0);

    // ---- ph2: issue A1 reads (8); MFMA M1N1 interleaved; then retire
    //           staging(kt+1) [exact: only those 8 in flight] + barrier.
#pragma unroll
    for (int i = 0; i < 4; ++i) {
      a[i][0] = ds_read128(Ab + 4096 + i * 1024 + sw0);
      a[i][1] = ds_read128(Ab + 4096 + i * 1024 + sw1);
    }
    __builtin_amdgcn_s_setprio(1);
    LGKM(6);
    G_AQ(0, 4, bq, 2)
    LGKM(4);
    G_AQ(1, 4, bq, 2)
    LGKM(2);
    G_AQ(2, 4, bq, 2)
    LGKM(0);
    G_AQ(3, 4, bq, 2)
    __builtin_amdgcn_s_setprio(0);
    VM(0);
    wg_barrier();  // buffer (kt+1)&1 now visible to all waves

    // ---- ph3: read B0(kt+1) -> bq (B1 dead; drains under next ph0's
    //           LGKM(6)); MFMA M1N0 -- all inputs resident, no wait.
    if (kn < NT) {
      const bf16_t* Bn = &Bs[(kn & 1) * 16384 + bRow];
#pragma unroll
      for (int j = 0; j < 2; ++j) {
        bq[j][0] = ds_read128(Bn + j * 1024 + sw0);
        bq[j][1] = ds_read128(Bn + j * 1024 + sw1);
      }
    }
    __builtin_amdgcn_s_setprio(1);
    G_AQ(0, 4, bc, 0)
    G_AQ(1, 4, bc, 0)
    G_AQ(2, 4, bc, 0)
    G_AQ(3, 4, bc, 0)
    __builtin_amdgcn_s_setprio(0);
  };

  for (int kt = 0; kt < NT; kt += 2) {
    tile_step(kt,     P, Q);   // bc = P holds B0(kt);   Q gets B1, B0(kt+1)
    tile_step(kt + 1, Q, P);   // bc = Q holds B0(kt+1); P gets B1, B0(kt+2)
  }

  // epilogue: 16x16 C map: col = lane&15, row = (lane>>4)*4 + r.
  // j innermost: 4 consecutive 32B segments per row -> 128B write-combining.
  float bvv[4];
#pragma unroll
  for (int j = 0; j < 4; ++j) {
    const int col = tileN + wn * 64 + j * 16 + r15;
    float bv = 0.f;
    if (NBIAS == 1) bv = b0[col];
    if (NBIAS == 3) {
      const float* bp = col < 1024 ? b0 : (col < 2048 ? b1 : b2);
      bv = bp[col & 1023];
    }
    bvv[j] = bv;
  }
#pragma unroll
  for (int i = 0; i < 8; ++i) {
#pragma unroll
    for (int r = 0; r < 4; ++r) {
      const long long row = tileM + wm * 128 + i * 16 + g * 4 + r;
      OutT* Crow = C + row * ldc + tileN + wn * 64 + r15;
#pragma unroll
      for (int j = 0; j < 4; ++j)
        store_out(Crow + j * 16, acc[i][j][r] * scale + bvv[j]);
    }
  }
}

// ---------------------------------------------------------------------------
// gemm128n_bt: 256Mx128N tile for N=1024 outputs (PV, out-proj). Same R10
// schedule; 8 waves as 4Mx2N -> wave tile 64x64 = 4x4 frags of 16x16x32.
// All fragment reads are 16-row => conflict-free with the chunk-XOR layout.
// LDS: As [2][256][64] 64KB + Bs [2][128][64] 32KB = 96KB (1 block/CU).
// Per-wave/K-tile: 16 ds_read_b128, 32 MFMA.
// Requires M%256==0, N%128==0, K%128==0 (NT even), gridDim.y%8==0.
// ---------------------------------------------------------------------------
template <typename OutT, int NBIAS>
__global__ __launch_bounds__(512, 2) void gemm128n_bt(
    const bf16_t* __restrict__ A, const bf16_t* __restrict__ B,
    OutT* __restrict__ C,
    const float* __restrict__ b0,
    int M, int N, int K, int lda, int ldb, int ldc, float scale,
    long long strideA, long long strideB, long long strideC) {
  const int z = blockIdx.z;
  A += (long long)z * strideA;
  B += (long long)z * strideB;
  C += (long long)z * strideC;

  // L2 supertile remap: 8 y-tiles per supertile, y-fastest inside.
  int bx = blockIdx.x, by = blockIdx.y;
  {
    const int GX  = gridDim.x;
    const int id  = by * GX + bx;
    const int per = GX * 8;
    const int grp = id / per;
    const int rem = id - grp * per;
    by = grp * 8 + (rem & 7);
    bx = rem >> 3;
  }

  __shared__ __align__(16) bf16_t As[2 * 256 * 64];  // 64 KB
  __shared__ __align__(16) bf16_t Bs[2 * 128 * 64];  // 32 KB

  const int t    = threadIdx.x;
  const int lane = t & 63;
  const int w    = t >> 6;
  const int wm   = w & 3;    // M quarter (64 rows)
  const int wn   = w >> 2;   // N half (64 cols)
  const int g    = lane >> 4;
  const int l7   = lane & 7;
  const int r15  = lane & 15;
  const int tileM = by * 256;
  const int tileN = bx * 128;

  const int row0 = t >> 3;                    // 0..63
  const int gcc  = (t & 7) ^ (row0 & 7);      // swizzled source chunk
  const int dstb = (t & ~63) * 8;             // wave-uniform LDS base (elems)

  const int sw0 = ((0 + g) ^ l7) * 8;
  const int sw1 = ((4 + g) ^ l7) * 8;
  const int aRow = (wm * 64 + r15) * 64;
  const int bRow = (wn * 64 + r15) * 64;

  const int NT = K >> 6;

  f32x4 acc[4][4] = {};

  auto stageA = [&](int kt, int h) {
    const int cb = (kt & 1) * 16384;
    const bf16_t* src =
        A + (long long)(tileM + h * 128 + row0) * lda + kt * 64 + gcc * 8;
    bf16_t* dst = &As[cb + h * 8192 + dstb];
    async_copy16(src, dst);
    async_copy16(src + (long long)64 * lda, dst + 4096);
  };
  auto stageB = [&](int kt) {
    const int cb = (kt & 1) * 8192;
    const bf16_t* src =
        B + (long long)(tileN + row0) * ldb + kt * 64 + gcc * 8;
    bf16_t* dst = &Bs[cb + dstb];
    async_copy16(src, dst);
    async_copy16(src + (long long)64 * ldb, dst + 4096);
  };

  // prologue: stage tile 0 (6 loads); retire; pre-read B0(0) (4 reads stay
  // outstanding into tile 0 ph0).
  stageA(0, 0); stageA(0, 1); stageB(0);
  VM(0);
  wg_barrier();

  bf16x8 a[2][2], P[2][2], Q[2][2];
#pragma unroll
  for (int j = 0; j < 2; ++j) {
    P[j][0] = ds_read128(&Bs[bRow + j * 1024 + sw0]);
    P[j][1] = ds_read128(&Bs[bRow + j * 1024 + sw1]);
  }

  // bc = B0(kt) [N-frags 0,1] read at prev ph3; bq = scratch (B1, B0-next).
  auto tile_step = [&](int kt, bf16x8 (&bc)[2][2], bf16x8 (&bq)[2][2]) {
    const int cb = (kt & 1) * 16384;
    const int kn = kt + 1;
    const bf16_t* Ab = &As[cb + aRow];
    const bf16_t* Bb = &Bs[(kt & 1) * 8192 + bRow];

    // ---- ph0: issue 4 A0 reads (outstanding 4+4=8); stage B(kt+1);
    //           MFMA M0(frags 0,1) x N0(bc) on counted lgkm.
    a[0][0] = ds_read128(Ab + sw0);
    a[0][1] = ds_read128(Ab + sw1);
    a[1][0] = ds_read128(Ab + 1024 + sw0);
    a[1][1] = ds_read128(Ab + 1024 + sw1);
    if (kn < NT) stageB(kn);
    __builtin_amdgcn_s_setprio(1);
    LGKM(3);  // retires bc x4 + a[0][0]
    acc[0][0] = mfma16(a[0][0], bc[0][0], acc[0][0]);
    acc[0][1] = mfma16(a[0][0], bc[1][0], acc[0][1]);
    LGKM(2);
    acc[0][0] = mfma16(a[0][1], bc[0][1], acc[0][0]);
    acc[0][1] = mfma16(a[0][1], bc[1][1], acc[0][1]);
    LGKM(1);
    acc[1][0] = mfma16(a[1][0], bc[0][0], acc[1][0]);
    acc[1][1] = mfma16(a[1][0], bc[1][0], acc[1][1]);
    LGKM(0);
    acc[1][0] = mfma16(a[1][1], bc[0][1], acc[1][0]);
    acc[1][1] = mfma16(a[1][1], bc[1][1], acc[1][1]);
    __builtin_amdgcn_s_setprio(0);

    // ---- ph1: issue 4 B1 reads -> bq; stage A(kt+1); MFMA M0 x N1.
    bq[0][0] = ds_read128(Bb + 2048 + sw0);
    bq[0][1] = ds_read128(Bb + 2048 + sw1);
    bq[1][0] = ds_read128(Bb + 3072 + sw0);
    bq[1][1] = ds_read128(Bb + 3072 + sw1);
    if (kn < NT) { stageA(kn, 0); stageA(kn, 1); }
    __builtin_amdgcn_s_setprio(1);
    LGKM(3);
    acc[0][2] = mfma16(a[0][0], bq[0][0], acc[0][2]);
    acc[1][2] = mfma16(a[1][0], bq[0][0], acc[1][2]);
    LGKM(2);
    acc[0][2] = mfma16(a[0][1], bq[0][1], acc[0][2]);
    acc[1][2] = mfma16(a[1][1], bq[0][1], acc[1][2]);
    LGKM(1);
    acc[0][3] = mfma16(a[0][0], bq[1][0], acc[0][3]);
    acc[1][3] = mfma16(a[1][0], bq[1][0], acc[1][3]);
    LGKM(0);
    acc[0][3] = mfma16(a[0][1], bq[1][1], acc[0][3]);
    acc[1][3] = mfma16(a[1][1], bq[1][1], acc[1][3]);
    __builtin_amdgcn_s_setprio(0);

    // ---- ph2: issue 4 A1 reads (frags 2,3); MFMA M1 x N1 (bq); exact
    //           VM(0) [6 staging loads, ~2 phases old]; barrier.
    a[0][0] = ds_read128(Ab + 2048 + sw0);
    a[0][1] = ds_read128(Ab + 2048 + sw1);
    a[1][0] = ds_read128(Ab + 3072 + sw0);
    a[1][1] = ds_read128(Ab + 3072 + sw1);
    __builtin_amdgcn_s_setprio(1);
    LGKM(3);
    acc[2][2] = mfma16(a[0][0], bq[0][0], acc[2][2]);
    acc[2][3] = mfma16(a[0][0], bq[1][0], acc[2][3]);
    LGKM(2);
    acc[2][2] = mfma16(a[0][1], bq[0][1], acc[2][2]);
    acc[2][3] = mfma16(a[0][1], bq[1][1], acc[2][3]);
    LGKM(1);
    acc[3][2] = mfma16(a[1][0], bq[0][0], acc[3][2]);
    acc[3][3] = mfma16(a[1][0], bq[1][0], acc[3][3]);
    LGKM(0);
    acc[3][2] = mfma16(a[1][1], bq[0][1], acc[3][2]);
    acc[3][3] = mfma16(a[1][1], bq[1][1], acc[3][3]);
    __builtin_amdgcn_s_setprio(0);
    VM(0);
    wg_barrier();  // buffer (kt+1)&1 now visible to all waves

    // ---- ph3: read B0(kt+1) -> bq (B1 dead; drains under next ph0's
    //           LGKM(3)); MFMA M1 x N0 (bc) reg-only.
    if (kn < NT) {
      const bf16_t* Bn = &Bs[(kn & 1) * 8192 + bRow];
      bq[0][0] = ds_read128(Bn + sw0);
      bq[0][1] = ds_read128(Bn + sw1);
      bq[1][0] = ds_read128(Bn + 1024 + sw0);
      bq[1][1] = ds_read128(Bn + 1024 + sw1);
    }
    __builtin_amdgcn_s_setprio(1);
    acc[2][0] = mfma16(a[0][0], bc[0][0], acc[2][0]);
    acc[2][0] = mfma16(a[0][1], bc[0][1], acc[2][0]);
    acc[2][1] = mfma16(a[0][0], bc[1][0], acc[2][1]);
    acc[2][1] = mfma16(a[0][1], bc[1][1], acc[2][1]);
    acc[3][0] = mfma16(a[1][0], bc[0][0], acc[3][0]);
    acc[3][0] = mfma16(a[1][1], bc[0][1], acc[3][0]);
    acc[3][1] = mfma16(a[1][0], bc[1][0], acc[3][1]);
    acc[3][1] = mfma16(a[1][1], bc[1][1], acc[3][1]);
    __builtin_amdgcn_s_setprio(0);
  };

  for (int kt = 0; kt < NT; kt += 2) {
    tile_step(kt,     P, Q);
    tile_step(kt + 1, Q, P);
  }

  // epilogue: 16x16 C map; j innermost for write combining.
  float bvv[4];
#pragma unroll
  for (int j = 0; j < 4; ++j) {
    const int col = tileN + wn * 64 + j * 16 + r15;
    bvv[j] = (NBIAS == 1) ? b0[col] : 0.f;
  }
#pragma unroll
  for (int i = 0; i < 4; ++i) {
#pragma unroll
    for (int r = 0; r < 4; ++r) {
      const long long row = tileM + wm * 64 + i * 16 + g * 4 + r;
      OutT* Crow = C + row * ldc + tileN + wn * 64 + r15;
#pragma unroll
      for (int j = 0; j < 4; ++j)
        store_out(Crow + j * 16, acc[i][j][r] * scale + bvv[j]);
    }
  }
}

// ---------------------------------------------------------------------------
// 128^2 kernel — small MT = Wk^T.Wq precompute only (64 blocks).
// ---------------------------------------------------------------------------
template <typename OutT, int NBIAS>
__global__ __launch_bounds__(256) void gemm_bt(
    const bf16_t* __restrict__ A, const bf16_t* __restrict__ B,
    OutT* __restrict__ C,
    const float* __restrict__ b0, const float* __restrict__ b1,
    const float* __restrict__ b2,
    int M, int N, int K, int lda, int ldb, int ldc, float scale,
    long long strideA, long long strideB, long long strideC) {
  const int z = blockIdx.z;
  A += (long long)z * strideA;
  B += (long long)z * strideB;
  C += (long long)z * strideC;

  int bx = blockIdx.x, by = blockIdx.y;
  {
    const int GX  = gridDim.x;
    const int id  = by * GX + bx;
    const int per = GX * 8;
    const int grp = id / per;
    const int rem = id - grp * per;
    by = grp * 8 + (rem & 7);
    bx = rem >> 3;
  }

  __shared__ __align__(16) bf16_t As[BM * BKT];  // 16 KB
  __shared__ __align__(16) bf16_t Bs[BN * BKT];  // 16 KB

  const int t    = threadIdx.x;
  const int lane = t & 63;
  const int w    = t >> 6;
  const int wm   = w & 1;
  const int wn   = w >> 1;
  const int tileM = by * BM;
  const int tileN = bx * BN;

  f32x16 acc[2][2] = {};

  for (int k0 = 0; k0 < K; k0 += BKT) {
#pragma unroll
    for (int i = 0; i < 4; ++i) {
      const int c   = t + 256 * i;
      const int row = c >> 3;
      const int cc  = c & 7;
      const int gcc = cc ^ (row & 7);
      const int ldsbase = ((t & ~63) + 256 * i) * 8;
      async_copy16(A + (long long)(tileM + row) * lda + k0 + gcc * 8, &As[ldsbase]);
      async_copy16(B + (long long)(tileN + row) * ldb + k0 + gcc * 8, &Bs[ldsbase]);
    }
    __syncthreads();

#pragma unroll
    for (int s = 0; s < 4; ++s) {
      const int kc = s + 4 * (lane >> 5);
      bf16x8 af[2], bfr[2];
#pragma unroll
      for (int ti = 0; ti < 2; ++ti) {
        const int row = wm * 64 + ti * 32 + (lane & 31);
        af[ti] = *(const bf16x8*)&As[row * BKT + ((kc ^ (row & 7)) * 8)];
      }
#pragma unroll
      for (int tj = 0; tj < 2; ++tj) {
        const int row = wn * 64 + tj * 32 + (lane & 31);
        bfr[tj] = *(const bf16x8*)&Bs[row * BKT + ((kc ^ (row & 7)) * 8)];
      }
#pragma unroll
      for (int ti = 0; ti < 2; ++ti)
#pragma unroll
        for (int tj = 0; tj < 2; ++tj)
          acc[ti][tj] = __builtin_amdgcn_mfma_f32_32x32x16_bf16(
              af[ti], bfr[tj], acc[ti][tj], 0, 0, 0);
    }
    __syncthreads();
  }

#pragma unroll
  for (int tj = 0; tj < 2; ++tj) {
    const int col = tileN + wn * 64 + tj * 32 + (lane & 31);
    float bv = 0.f;
    if (NBIAS == 1) bv = b0[col];
    if (NBIAS == 3) {
      const float* bp = col < 1024 ? b0 : (col < 2048 ? b1 : b2);
      bv = bp[col & 1023];
    }
#pragma unroll
    for (int ti = 0; ti < 2; ++ti) {
      const int rowb = tileM + wm * 64 + ti * 32 + 4 * (lane >> 5);
#pragma unroll
      for (int r = 0; r < 16; ++r) {
        const int row = rowb + (r & 3) + 8 * (r >> 2);
        store_out(&C[(long long)row * ldc + col], acc[ti][tj][r] * scale + bv);
      }
    }
  }
}

// ---------------------------------------------------------------------------
// fused cast: 4 weights (separate dsts) + x in one dispatch.
// ---------------------------------------------------------------------------
__global__ __launch_bounds__(256) void cast_all(
    const float4* __restrict__ w0, const float4* __restrict__ w1,
    const float4* __restrict__ w2, const float4* __restrict__ w3,
    const float4* __restrict__ x,
    bf16x4* __restrict__ d0, bf16x4* __restrict__ d1,
    bf16x4* __restrict__ d2, bf16x4* __restrict__ d3,
    bf16x4* __restrict__ xdst) {
  const int N4W = 1 << 18;  // 1024*1024/4
  const int id = blockIdx.x * 256 + threadIdx.x;
  const float4* src;
  bf16x4* dst;
  if (id < 4 * N4W) {
    const int z = id >> 18;
    const int i = id & (N4W - 1);
    src = (z == 0 ? w0 : z == 1 ? w1 : z == 2 ? w2 : w3) + i;
    dst = (z == 0 ? d0 : z == 1 ? d1 : z == 2 ? d2 : d3) + i;
  } else {
    const int i = id - 4 * N4W;
    src = x + i;
    dst = xdst + i;
  }
  const float4 v = *src;
  bf16x4 o;
  o[0] = (bf16_t)v.x; o[1] = (bf16_t)v.y; o[2] = (bf16_t)v.z; o[3] = (bf16_t)v.w;
  *dst = o;
}

// ---------------------------------------------------------------------------
// v = bq . Wk via WkT rows: one wave per output column (grid 256 x 4 waves).
// ---------------------------------------------------------------------------
__global__ __launch_bounds__(256) void bias_v(
    const bf16_t* __restrict__ WkT, const float* __restrict__ bq,
    float* __restrict__ v) {
  const int wv   = threadIdx.x >> 6;
  const int lane = threadIdx.x & 63;
  const int j    = blockIdx.x * 4 + wv;  // grid 256 -> j in [0,1024)
  const bf16x8* row = (const bf16x8*)(WkT + (long long)j * 1024);
  float acc = 0.f;
#pragma unroll
  for (int h = 0; h < 2; ++h) {
    const bf16x8 w8 = row[lane * 2 + h];
#pragma unroll
    for (int e = 0; e < 8; ++e)
      acc += (float)w8[e] * bq[lane * 16 + h * 8 + e];
  }
#pragma unroll
  for (int off = 32; off > 0; off >>= 1) acc += __shfl_xor(acc, off);
  if (lane == 0) v[j] = acc;
}

// ---------------------------------------------------------------------------
// bf16 transpose [R,C](ldin) -> [C,R], batched via blockIdx.z
// ---------------------------------------------------------------------------
__global__ __launch_bounds__(256) void transpose_bf16(
    const bf16_t* __restrict__ in, bf16_t* __restrict__ out, int R, int C,
    int ldin, long long sIn, long long sOut) {
  in  += (long long)blockIdx.z * sIn;
  out += (long long)blockIdx.z * sOut;
  __shared__ bf16_t tile[32][33];
  const int tx = threadIdx.x, ty = threadIdx.y;
  const int x = blockIdx.x * 32 + tx;
  const int y0 = blockIdx.y * 32;
#pragma unroll
  for (int j = 0; j < 32; j += 8)
    tile[ty + j][tx] = in[(long long)(y0 + ty + j) * ldin + x];
  __syncthreads();
  const int x2 = y0 + tx;
  const int y2 = blockIdx.x * 32;
#pragma unroll
  for (int j = 0; j < 32; j += 8)
    out[(long long)(y2 + ty + j) * R + x2] = tile[tx][ty + j];
}

// ---------------------------------------------------------------------------
// row softmax: 2048-wide rows, 256 threads x 8 elems
// ---------------------------------------------------------------------------
__global__ __launch_bounds__(256) void softmax_rows(
    const bf16_t* __restrict__ S, bf16_t* __restrict__ P, int cols) {
  const long long row = blockIdx.x;
  const bf16x8* inp = (const bf16x8*)(S + row * cols);
  bf16x8* outp      = (bf16x8*)(P + row * cols);
  const int t = threadIdx.x;
  const int w = t >> 6, lane = t & 63;

  const bf16x8 v = inp[t];
  float f[8];
#pragma unroll
  for (int j = 0; j < 8; ++j) f[j] = (float)v[j];

  float m = f[0];
#pragma unroll
  for (int j = 1; j < 8; ++j) m = fmaxf(m, f[j]);
#pragma unroll
  for (int off = 32; off > 0; off >>= 1) m = fmaxf(m, __shfl_xor(m, off));

  __shared__ float red[8];
  if (lane == 0) red[w] = m;
  __syncthreads();
  m = fmaxf(fmaxf(red[0], red[1]), fmaxf(red[2], red[3]));

  float e[8], sum = 0.f;
#pragma unroll
  for (int j = 0; j < 8; ++j) { e[j] = __expf(f[j] - m); sum += e[j]; }
#pragma unroll
  for (int off = 32; off > 0; off >>= 1) sum += __shfl_xor(sum, off);
  if (lane == 0) red[4 + w] = sum;
  __syncthreads();
  sum = red[4] + red[5] + red[6] + red[7];

  const float inv = 1.f / sum;
  bf16x8 o;
#pragma unroll
  for (int j = 0; j < 8; ++j) o[j] = (bf16_t)(e[j] * inv);
  outp[t] = o;
}

// ---------------------------------------------------------------------------
extern "C" void kernel_launch(void* const* d_in, const int* in_sizes, int n_in,
                              void* d_out, int out_size, void* d_ws, size_t ws_size,
                              hipStream_t stream) {
  const int E = 1024, S = 2048, B = 4;
  const int BS = B * S;  // 8192

  const float* x  = (const float*)d_in[0];
  const float* Wq = (const float*)d_in[1];
  const float* bq = (const float*)d_in[2];
  const float* Wk = (const float*)d_in[3];
  const float* bk = (const float*)d_in[4];
  const float* Wv = (const float*)d_in[5];
  const float* bv = (const float*)d_in[6];
  const float* Wo = (const float*)d_in[7];
  const float* bo = (const float*)d_in[8];
  float* out = (float*)d_out;
  (void)bk; (void)Wk;  // bk algebraically eliminated; Wk used via bf16 copy

  char* w = (char*)d_ws;
  const size_t MB = 1ull << 20;
  bf16_t* Wqb  = (bf16_t*)(w + 0 * MB);           // 2 MB  Wq bf16
  bf16_t* Wkb  = Wqb + E * E;                     // 2 MB  Wk bf16
  bf16_t* Wob  = (bf16_t*)(w + 4 * MB);           // 2 MB
  float*  vb   = (float*)(w + 6 * MB);            // 4 KB  v = bq.Wk
  bf16_t* xb   = (bf16_t*)(w + 8 * MB);           // 16 MB [8192,1024]
  bf16_t* QVb  = (bf16_t*)(w + 24 * MB);          // 32 MB [8192,2048] = [G|V]
  bf16_t* WqTb = (bf16_t*)(w + 56 * MB);          // 2 MB
  bf16_t* WkTb = WqTb + E * E;                    // 2 MB
  bf16_t* Wqv  = (bf16_t*)(w + 60 * MB);          // 4 MB [MT(1024); Wv(1024)]
  bf16_t* Wvb  = Wqv + E * E;                     //   (Wv rows of Wqv)
  bf16_t* VTb  = (bf16_t*)(w + 72 * MB);          // 16 MB [B][1024,2048]
  bf16_t* Sb   = (bf16_t*)(w + 88 * MB);          // 32 MB scores
  bf16_t* Pb   = (bf16_t*)(w + 8 * MB);           // 32 MB (xb dead after scores)
  bf16_t* Ob   = (bf16_t*)(w + 40 * MB);          // 16 MB (QVb[16:32MB] dead)

  // ---- all casts in one dispatch
  {
    const int totalBlocks = ((4 << 18) + (1 << 21)) / 256;  // 12288
    cast_all<<<totalBlocks, 256, 0, stream>>>(
        (const float4*)Wq, (const float4*)Wk, (const float4*)Wv,
        (const float4*)Wo, (const float4*)x,
        (bf16x4*)Wqb, (bf16x4*)Wkb, (bf16x4*)Wvb, (bf16x4*)Wob, (bf16x4*)xb);
  }

  // ---- WqT, WkT (one batched dispatch, z=2)
  transpose_bf16<<<dim3(E / 32, E / 32, 2), dim3(32, 8), 0, stream>>>(
      Wqb, WqTb, E, E, E, (long long)E * E, (long long)E * E);

  // ---- v = bq . Wk = WkT-row dot bq (wave per column)
  bias_v<<<256, 256, 0, stream>>>(WkTb, bq, vb);

  // ---- MT = Wk^T . Wq : gemm_bt(A=WkT, B=WqT) -> Wqv rows 0..1023
  gemm_bt<bf16_t, 0><<<dim3(E / BN, E / BM, 1), 256, 0, stream>>>(
      WkTb, WqTb, Wqv, nullptr, nullptr, nullptr,
      E, E, E, E, E, E, 1.f, 0, 0, 0);

  // ---- fused [G|V] projection: [8192,2048] = xb . Wqv^T + (v|bv)
  gemm256_bt<bf16_t, 3><<<dim3(2 * E / 256, BS / 256, 1), 512, 0, stream>>>(
      xb, Wqv, QVb, vb, bv, bv,
      BS, 2 * E, E, E, E, 2 * E, 1.f, 0, 0, 0);

  // ---- V^T per batch: [2048,1024](ld 2048) -> [1024,2048]
  transpose_bf16<<<dim3(E / 32, S / 32, B), dim3(32, 8), 0, stream>>>(
      QVb + E, VTb, S, E, 2 * E, (long long)S * 2 * E, (long long)E * S);

  // ---- scores' = G . x^T * E^-0.5 per batch
  gemm256_bt<bf16_t, 0><<<dim3(S / 256, S / 256, B), 512, 0, stream>>>(
      QVb, xb, Sb, nullptr, nullptr, nullptr,
      S, S, E, 2 * E, E, S, 0.03125f,
      (long long)S * 2 * E, (long long)S * E, (long long)S * S);

  // ---- softmax
  softmax_rows<<<BS, 256, 0, stream>>>(Sb, Pb, S);

  // ---- O = P . (V^T)^T per batch  (256Mx128N kernel, 256 blocks)
  gemm128n_bt<bf16_t, 0><<<dim3(E / 128, S / 256, B), 512, 0, stream>>>(
      Pb, VTb, Ob, nullptr,
      S, E, S, S, S, E, 1.f,
      (long long)S * S, (long long)E * S, (long long)S * E);

  // ---- y = O . Wo^T + bo  (256Mx128N kernel, 256 blocks)
  gemm128n_bt<float, 1><<<dim3(E / 128, BS / 256, 1), 512, 0, stream>>>(
      Ob, Wob, out, bo,
      BS, E, E, E, E, E, 1.f, 0, 0, 0);
}

// Round 10
// 281.464 us; speedup vs baseline: 1.3359x; 1.0009x over previous
//
#include <hip/hip_runtime.h>
#include <hip/hip_bf16.h>

// ---------------------------------------------------------------------------
// SelfAttentionHybrid: single-head attention, B=4 S=2048 E=1024, fp32 in/out.
// R16: gemm128_bt2 = R15's conflict-free wave schedule at 2 blocks/CU.
// R15 post-mortem: conflict-free gemm128n (1 block/CU, 96KB) was SLOWER for
// PV (52.2) than the old conflicted 2-block 128^2 kernel (45.8) -- the old
// kernel's second resident block hid the per-tile VM(0)+barrier staging
// stalls (cross-block TLP). Cold-stream GEMMs (PV, out-proj: both operands
// HBM/L2-cold) stall long at the drain; QV (L2-hot weights) doesn't.
// gemm128_bt2: 128x128 tile, 256 thr / 4 waves (2Mx2N), wave tile 64x64 =
// 4x4 16x16 frags, LDS 2buf 64KB -> 2 blocks/CU; counted-lgkm ladder,
// 1 barrier/tile, exact VM(0) -- per-wave body identical to gemm128n.
// PV grid (8,16,4)=512 = 2/CU one round; out-proj (8,64)=512.
//
// Algebra (R13, verified): softmax shift-invariance =>
//   S = q.k^T == x.M.x^T + v.x^T (+row-const), M = Wq^T.Wk, v = bq.Wk.
// ---------------------------------------------------------------------------

typedef __bf16 bf16_t;
typedef __bf16 bf16x8 __attribute__((ext_vector_type(8)));
typedef __bf16 bf16x4 __attribute__((ext_vector_type(4)));
typedef float  f32x16 __attribute__((ext_vector_type(16)));
typedef float  f32x4  __attribute__((ext_vector_type(4)));

__device__ __forceinline__ void async_copy16(const void* g, void* l) {
  __builtin_amdgcn_global_load_lds(
      (const __attribute__((address_space(1))) void*)g,
      (__attribute__((address_space(3))) void*)l, 16, 0, 0);
}

// raw workgroup barrier: NO vmcnt/lgkmcnt drain (unlike __syncthreads).
__device__ __forceinline__ void wg_barrier() {
  asm volatile("" ::: "memory");
  __builtin_amdgcn_s_barrier();
  asm volatile("" ::: "memory");
}

// counted LDS wait + rule-18 scheduler pin (MFMAs must not hoist above it)
#define LGKM(n)                                                  \
  do {                                                           \
    asm volatile("s_waitcnt lgkmcnt(" #n ")" ::: "memory");      \
    __builtin_amdgcn_sched_barrier(0);                           \
  } while (0)

#define VM(n) asm volatile("s_waitcnt vmcnt(" #n ")" ::: "memory")

// 32-bit LDS byte address (for asm ds_read; invisible to alias analysis)
__device__ __forceinline__ unsigned lds_addr(const void* p) {
  return (unsigned)(unsigned long long)(__attribute__((address_space(3))) const void*)p;
}

// inline-asm LDS read: compiler cannot see this as an LDS access, so it does
// NOT insert vmcnt(0) ordering vs in-flight global_load_lds prefetches.
// Ordering enforced manually via LGKM() + the per-tile vmcnt/barrier.
__device__ __forceinline__ bf16x8 ds_read128(const bf16_t* p) {
  bf16x8 r;
  asm volatile("ds_read_b128 %0, %1" : "=v"(r) : "v"(lds_addr(p)));
  return r;
}

__device__ __forceinline__ f32x4 mfma16(bf16x8 a, bf16x8 b, f32x4 c) {
  return __builtin_amdgcn_mfma_f32_16x16x32_bf16(a, b, c, 0, 0, 0);
}

__device__ __forceinline__ void store_out(float* p, float v)  { *p = v; }
__device__ __forceinline__ void store_out(bf16_t* p, float v) { *p = (bf16_t)v; }

#define BM 128
#define BN 128
#define BKT 64

// 4 MFMA: a[i] x bb -> acc[ro+i][co..co+1], both k-slices
#define G_AQ(i, ro, bb, co)                                                   \
  acc[(ro) + (i)][(co) + 0] = mfma16(a[i][0], bb[0][0], acc[(ro) + (i)][(co) + 0]); \
  acc[(ro) + (i)][(co) + 1] = mfma16(a[i][0], bb[1][0], acc[(ro) + (i)][(co) + 1]); \
  acc[(ro) + (i)][(co) + 0] = mfma16(a[i][1], bb[0][1], acc[(ro) + (i)][(co) + 0]); \
  acc[(ro) + (i)][(co) + 1] = mfma16(a[i][1], bb[1][1], acc[(ro) + (i)][(co) + 1]);

// 8 MFMA: all a[i] x bb[j] -> acc[0..3][co+j], both k-slices
#define G_BQ(j, bb, co)                                              \
  acc[0][(co) + (j)] = mfma16(a[0][0], bb[j][0], acc[0][(co) + (j)]); \
  acc[1][(co) + (j)] = mfma16(a[1][0], bb[j][0], acc[1][(co) + (j)]); \
  acc[2][(co) + (j)] = mfma16(a[2][0], bb[j][0], acc[2][(co) + (j)]); \
  acc[3][(co) + (j)] = mfma16(a[3][0], bb[j][0], acc[3][(co) + (j)]); \
  acc[0][(co) + (j)] = mfma16(a[0][1], bb[j][1], acc[0][(co) + (j)]); \
  acc[1][(co) + (j)] = mfma16(a[1][1], bb[j][1], acc[1][(co) + (j)]); \
  acc[2][(co) + (j)] = mfma16(a[2][1], bb[j][1], acc[2][(co) + (j)]); \
  acc[3][(co) + (j)] = mfma16(a[3][1], bb[j][1], acc[3][(co) + (j)]);

// ---------------------------------------------------------------------------
// gemm256_bt (R10 config): C[M,N] = A[M,K](lda) x B[N,K](ldb)^T * scale + b.
// 512 thr = 8 waves (2Mx4N); wave tile 128x64 = 8x4 frags of 16x16x32 MFMA.
// LDS [2 buf][256 rows][64 bf16] per matrix; slot (r,cc) holds global chunk
// cc^(r&7); reads use slot kc^(r&7) (involution; 16-row instrs => 2-way max,
// measured 0 conflicts).
// Requires M%256==0, N%256==0, K%128==0 (NT even), gridDim.y%8==0.
// ---------------------------------------------------------------------------
template <typename OutT, int NBIAS>
__global__ __launch_bounds__(512, 2) void gemm256_bt(
    const bf16_t* __restrict__ A, const bf16_t* __restrict__ B,
    OutT* __restrict__ C,
    const float* __restrict__ b0, const float* __restrict__ b1,
    const float* __restrict__ b2,
    int M, int N, int K, int lda, int ldb, int ldc, float scale,
    long long strideA, long long strideB, long long strideC) {
  const int z = blockIdx.z;
  A += (long long)z * strideA;
  B += (long long)z * strideB;
  C += (long long)z * strideC;

  // L2 supertile remap: 8 y-tiles per supertile, y-fastest inside.
  int bx = blockIdx.x, by = blockIdx.y;
  {
    const int GX  = gridDim.x;
    const int id  = by * GX + bx;
    const int per = GX * 8;
    const int grp = id / per;
    const int rem = id - grp * per;
    by = grp * 8 + (rem & 7);
    bx = rem >> 3;
  }

  __shared__ __align__(16) bf16_t As[2 * 256 * 64];  // 64 KB
  __shared__ __align__(16) bf16_t Bs[2 * 256 * 64];  // 64 KB

  const int t    = threadIdx.x;
  const int lane = t & 63;
  const int w    = t >> 6;
  const int wm   = w & 1;    // M-half of output tile
  const int wn   = w >> 1;   // N-quarter of output tile
  const int g    = lane >> 4;
  const int l7   = lane & 7;
  const int r15  = lane & 15;
  const int tileM = by * 256;
  const int tileN = bx * 256;

  // staging constants: thread covers chunks t and t+512 of each half-tile
  const int row0 = t >> 3;                    // 0..63
  const int gcc  = (t & 7) ^ (row0 & 7);      // swizzled source chunk
  const int dstb = (t & ~63) * 8;             // wave-uniform LDS base (elems)

  // read constants
  const int sw0 = ((0 + g) ^ l7) * 8;         // k-slice 0 chunk offset (elems)
  const int sw1 = ((4 + g) ^ l7) * 8;         // k-slice 1
  const int aRow = (wm * 128 + r15) * 64;
  const int bRow = (wn * 64 + r15) * 64;

  const int NT = K >> 6;

  f32x4 acc[8][4] = {};

  auto stageA = [&](int kt, int h) {
    const int cb = (kt & 1) * 16384;
    const bf16_t* src =
        A + (long long)(tileM + h * 128 + row0) * lda + kt * 64 + gcc * 8;
    bf16_t* dst = &As[cb + h * 8192 + dstb];
    async_copy16(src, dst);
    async_copy16(src + (long long)64 * lda, dst + 4096);
  };
  auto stageB = [&](int kt, int h) {
    const int cb = (kt & 1) * 16384;
    const bf16_t* src =
        B + (long long)(tileN + h * 128 + row0) * ldb + kt * 64 + gcc * 8;
    bf16_t* dst = &Bs[cb + h * 8192 + dstb];
    async_copy16(src, dst);
    async_copy16(src + (long long)64 * ldb, dst + 4096);
  };

  // prologue: stage tile 0 only; retire; pre-read B0(0) (4 reads stay
  // outstanding into tile 0 ph0 -- steady-state invariant).
  stageA(0, 0); stageA(0, 1); stageB(0, 0); stageB(0, 1);
  VM(0);
  wg_barrier();

  bf16x8 a[4][2], P[2][2], Q[2][2];
#pragma unroll
  for (int j = 0; j < 2; ++j) {
    P[j][0] = ds_read128(&Bs[bRow + j * 1024 + sw0]);
    P[j][1] = ds_read128(&Bs[bRow + j * 1024 + sw1]);
  }

  // bc = B0(kt) (read at prev ph3); bq = scratch: gets B1(kt) then B0(kt+1)
  auto tile_step = [&](int kt, bf16x8 (&bc)[2][2], bf16x8 (&bq)[2][2]) {
    const int cb = (kt & 1) * 16384;
    const int kn = kt + 1;
    const bf16_t* Ab = &As[cb + aRow];
    const bf16_t* Bb = &Bs[cb + bRow];

    // ---- ph0: issue A0 reads (outstanding 4+8=12); stage B(kt+1);
    //           MFMA M0N0 interleaved on counted lgkm.
#pragma unroll
    for (int i = 0; i < 4; ++i) {
      a[i][0] = ds_read128(Ab + i * 1024 + sw0);
      a[i][1] = ds_read128(Ab + i * 1024 + sw1);
    }
    if (kn < NT) { stageB(kn, 0); stageB(kn, 1); }
    __builtin_amdgcn_s_setprio(1);
    LGKM(6);  // retires B0(kt) x4 + a[0] pair
    G_AQ(0, 0, bc, 0)
    LGKM(4);
    G_AQ(1, 0, bc, 0)
    LGKM(2);
    G_AQ(2, 0, bc, 0)
    LGKM(0);
    G_AQ(3, 0, bc, 0)
    __builtin_amdgcn_s_setprio(0);

    // ---- ph1: issue B1 reads (4); stage A(kt+1); MFMA M0N1 interleaved.
#pragma unroll
    for (int j = 0; j < 2; ++j) {
      bq[j][0] = ds_read128(Bb + 2048 + j * 1024 + sw0);
      bq[j][1] = ds_read128(Bb + 2048 + j * 1024 + sw1);
    }
    if (kn < NT) { stageA(kn, 0); stageA(kn, 1); }
    __builtin_amdgcn_s_setprio(1);
    LGKM(2);  // bq[0] ready
    G_BQ(0, bq, 2)
    LGKM(0);  // bq[1] ready
    G_BQ(1, bq, 2)
    __builtin_amdgcn_s_setprio(0);

    // ---- ph2: issue A1 reads (8); MFMA M1N1 interleaved; then retire
    //           staging(kt+1) [exact: only those 8 in flight] + barrier.
#pragma unroll
    for (int i = 0; i < 4; ++i) {
      a[i][0] = ds_read128(Ab + 4096 + i * 1024 + sw0);
      a[i][1] = ds_read128(Ab + 4096 + i * 1024 + sw1);
    }
    __builtin_amdgcn_s_setprio(1);
    LGKM(6);
    G_AQ(0, 4, bq, 2)
    LGKM(4);
    G_AQ(1, 4, bq, 2)
    LGKM(2);
    G_AQ(2, 4, bq, 2)
    LGKM(0);
    G_AQ(3, 4, bq, 2)
    __builtin_amdgcn_s_setprio(0);
    VM(0);
    wg_barrier();  // buffer (kt+1)&1 now visible to all waves

    // ---- ph3: read B0(kt+1) -> bq (B1 dead; drains under next ph0's
    //           LGKM(6)); MFMA M1N0 -- all inputs resident, no wait.
    if (kn < NT) {
      const bf16_t* Bn = &Bs[(kn & 1) * 16384 + bRow];
#pragma unroll
      for (int j = 0; j < 2; ++j) {
        bq[j][0] = ds_read128(Bn + j * 1024 + sw0);
        bq[j][1] = ds_read128(Bn + j * 1024 + sw1);
      }
    }
    __builtin_amdgcn_s_setprio(1);
    G_AQ(0, 4, bc, 0)
    G_AQ(1, 4, bc, 0)
    G_AQ(2, 4, bc, 0)
    G_AQ(3, 4, bc, 0)
    __builtin_amdgcn_s_setprio(0);
  };

  for (int kt = 0; kt < NT; kt += 2) {
    tile_step(kt,     P, Q);   // bc = P holds B0(kt);   Q gets B1, B0(kt+1)
    tile_step(kt + 1, Q, P);   // bc = Q holds B0(kt+1); P gets B1, B0(kt+2)
  }

  // epilogue: 16x16 C map: col = lane&15, row = (lane>>4)*4 + r.
  // j innermost: 4 consecutive 32B segments per row -> 128B write-combining.
  float bvv[4];
#pragma unroll
  for (int j = 0; j < 4; ++j) {
    const int col = tileN + wn * 64 + j * 16 + r15;
    float bv = 0.f;
    if (NBIAS == 1) bv = b0[col];
    if (NBIAS == 3) {
      const float* bp = col < 1024 ? b0 : (col < 2048 ? b1 : b2);
      bv = bp[col & 1023];
    }
    bvv[j] = bv;
  }
#pragma unroll
  for (int i = 0; i < 8; ++i) {
#pragma unroll
    for (int r = 0; r < 4; ++r) {
      const long long row = tileM + wm * 128 + i * 16 + g * 4 + r;
      OutT* Crow = C + row * ldc + tileN + wn * 64 + r15;
#pragma unroll
      for (int j = 0; j < 4; ++j)
        store_out(Crow + j * 16, acc[i][j][r] * scale + bvv[j]);
    }
  }
}

// ---------------------------------------------------------------------------
// gemm128_bt2: 128x128 tile, 256 thr / 4 waves (2Mx2N), wave tile 64x64 =
// 4x4 frags of 16x16x32. LDS 2buf As[2][128][64]+Bs[2][128][64] = 64KB ->
// 2 blocks/CU (cross-block TLP hides the per-tile VM(0)+barrier drain --
// the R15 lesson). Same counted-lgkm ladder / 1 barrier/tile as gemm128n.
// All fragment reads 16-row => conflict-free with chunk-XOR layout.
// Per-wave/K-tile: 16 ds_read_b128, 32 MFMA.
// Requires M%128==0, N%128==0, K%128==0 (NT even), gridDim.y%8==0.
// ---------------------------------------------------------------------------
template <typename OutT, int NBIAS>
__global__ __launch_bounds__(256, 2) void gemm128_bt2(
    const bf16_t* __restrict__ A, const bf16_t* __restrict__ B,
    OutT* __restrict__ C,
    const float* __restrict__ b0,
    int M, int N, int K, int lda, int ldb, int ldc, float scale,
    long long strideA, long long strideB, long long strideC) {
  const int z = blockIdx.z;
  A += (long long)z * strideA;
  B += (long long)z * strideB;
  C += (long long)z * strideC;

  // L2 supertile remap: 8 y-tiles per supertile, y-fastest inside.
  int bx = blockIdx.x, by = blockIdx.y;
  {
    const int GX  = gridDim.x;
    const int id  = by * GX + bx;
    const int per = GX * 8;
    const int grp = id / per;
    const int rem = id - grp * per;
    by = grp * 8 + (rem & 7);
    bx = rem >> 3;
  }

  __shared__ __align__(16) bf16_t As[2 * 128 * 64];  // 32 KB
  __shared__ __align__(16) bf16_t Bs[2 * 128 * 64];  // 32 KB

  const int t    = threadIdx.x;
  const int lane = t & 63;
  const int w    = t >> 6;
  const int wm   = w & 1;    // M half (64 rows)
  const int wn   = w >> 1;   // N half (64 cols)
  const int g    = lane >> 4;
  const int l7   = lane & 7;
  const int r15  = lane & 15;
  const int tileM = by * 128;
  const int tileN = bx * 128;

  const int sw0 = ((0 + g) ^ l7) * 8;
  const int sw1 = ((4 + g) ^ l7) * 8;
  const int aRow = (wm * 64 + r15) * 64;
  const int bRow = (wn * 64 + r15) * 64;

  const int NT = K >> 6;

  f32x4 acc[4][4] = {};

  auto stageA = [&](int kt) {
    const int cb = (kt & 1) * 8192;
#pragma unroll
    for (int i = 0; i < 4; ++i) {
      const int c   = t + 256 * i;
      const int row = c >> 3;
      const int cc  = c & 7;
      const int gcc = cc ^ (row & 7);
      const int ldsbase = ((t & ~63) + 256 * i) * 8;
      async_copy16(A + (long long)(tileM + row) * lda + kt * 64 + gcc * 8,
                   &As[cb + ldsbase]);
    }
  };
  auto stageB = [&](int kt) {
    const int cb = (kt & 1) * 8192;
#pragma unroll
    for (int i = 0; i < 4; ++i) {
      const int c   = t + 256 * i;
      const int row = c >> 3;
      const int cc  = c & 7;
      const int gcc = cc ^ (row & 7);
      const int ldsbase = ((t & ~63) + 256 * i) * 8;
      async_copy16(B + (long long)(tileN + row) * ldb + kt * 64 + gcc * 8,
                   &Bs[cb + ldsbase]);
    }
  };

  // prologue: stage tile 0 (8 copies); retire; pre-read B0(0) (4 reads stay
  // outstanding into tile 0 ph0).
  stageA(0); stageB(0);
  VM(0);
  wg_barrier();

  bf16x8 a[2][2], P[2][2], Q[2][2];
#pragma unroll
  for (int j = 0; j < 2; ++j) {
    P[j][0] = ds_read128(&Bs[bRow + j * 1024 + sw0]);
    P[j][1] = ds_read128(&Bs[bRow + j * 1024 + sw1]);
  }

  // bc = B0(kt) [N-frags 0,1] read at prev ph3; bq = scratch (B1, B0-next).
  auto tile_step = [&](int kt, bf16x8 (&bc)[2][2], bf16x8 (&bq)[2][2]) {
    const int cb = (kt & 1) * 8192;
    const int kn = kt + 1;
    const bf16_t* Ab = &As[cb + aRow];
    const bf16_t* Bb = &Bs[cb + bRow];

    // ---- ph0: issue 4 A0 reads (outstanding 4+4=8); stage B(kt+1);
    //           MFMA M0,M1 x N0,N1 (bc) on counted lgkm.
    a[0][0] = ds_read128(Ab + sw0);
    a[0][1] = ds_read128(Ab + sw1);
    a[1][0] = ds_read128(Ab + 1024 + sw0);
    a[1][1] = ds_read128(Ab + 1024 + sw1);
    if (kn < NT) stageB(kn);
    __builtin_amdgcn_s_setprio(1);
    LGKM(3);  // retires bc x4 + a[0][0]
    acc[0][0] = mfma16(a[0][0], bc[0][0], acc[0][0]);
    acc[0][1] = mfma16(a[0][0], bc[1][0], acc[0][1]);
    LGKM(2);
    acc[0][0] = mfma16(a[0][1], bc[0][1], acc[0][0]);
    acc[0][1] = mfma16(a[0][1], bc[1][1], acc[0][1]);
    LGKM(1);
    acc[1][0] = mfma16(a[1][0], bc[0][0], acc[1][0]);
    acc[1][1] = mfma16(a[1][0], bc[1][0], acc[1][1]);
    LGKM(0);
    acc[1][0] = mfma16(a[1][1], bc[0][1], acc[1][0]);
    acc[1][1] = mfma16(a[1][1], bc[1][1], acc[1][1]);
    __builtin_amdgcn_s_setprio(0);

    // ---- ph1: issue 4 B1 reads -> bq; stage A(kt+1); MFMA M0,M1 x N2,N3.
    bq[0][0] = ds_read128(Bb + 2048 + sw0);
    bq[0][1] = ds_read128(Bb + 2048 + sw1);
    bq[1][0] = ds_read128(Bb + 3072 + sw0);
    bq[1][1] = ds_read128(Bb + 3072 + sw1);
    if (kn < NT) stageA(kn);
    __builtin_amdgcn_s_setprio(1);
    LGKM(3);
    acc[0][2] = mfma16(a[0][0], bq[0][0], acc[0][2]);
    acc[1][2] = mfma16(a[1][0], bq[0][0], acc[1][2]);
    LGKM(2);
    acc[0][2] = mfma16(a[0][1], bq[0][1], acc[0][2]);
    acc[1][2] = mfma16(a[1][1], bq[0][1], acc[1][2]);
    LGKM(1);
    acc[0][3] = mfma16(a[0][0], bq[1][0], acc[0][3]);
    acc[1][3] = mfma16(a[1][0], bq[1][0], acc[1][3]);
    LGKM(0);
    acc[0][3] = mfma16(a[0][1], bq[1][1], acc[0][3]);
    acc[1][3] = mfma16(a[1][1], bq[1][1], acc[1][3]);
    __builtin_amdgcn_s_setprio(0);

    // ---- ph2: issue 4 A1 reads (frags M2,M3); MFMA M2,M3 x N2,N3 (bq);
    //           exact VM(0) [8 staging copies in flight]; barrier.
    a[0][0] = ds_read128(Ab + 2048 + sw0);
    a[0][1] = ds_read128(Ab + 2048 + sw1);
    a[1][0] = ds_read128(Ab + 3072 + sw0);
    a[1][1] = ds_read128(Ab + 3072 + sw1);
    __builtin_amdgcn_s_setprio(1);
    LGKM(3);
    acc[2][2] = mfma16(a[0][0], bq[0][0], acc[2][2]);
    acc[2][3] = mfma16(a[0][0], bq[1][0], acc[2][3]);
    LGKM(2);
    acc[2][2] = mfma16(a[0][1], bq[0][1], acc[2][2]);
    acc[2][3] = mfma16(a[0][1], bq[1][1], acc[2][3]);
    LGKM(1);
    acc[3][2] = mfma16(a[1][0], bq[0][0], acc[3][2]);
    acc[3][3] = mfma16(a[1][0], bq[1][0], acc[3][3]);
    LGKM(0);
    acc[3][2] = mfma16(a[1][1], bq[0][1], acc[3][2]);
    acc[3][3] = mfma16(a[1][1], bq[1][1], acc[3][3]);
    __builtin_amdgcn_s_setprio(0);
    VM(0);
    wg_barrier();  // buffer (kt+1)&1 now visible to all waves

    // ---- ph3: read B0(kt+1) -> bq (B1 dead; drains under next ph0's
    //           LGKM(3)); MFMA M2,M3 x N0,N1 (bc) reg-only.
    if (kn < NT) {
      const bf16_t* Bn = &Bs[(kn & 1) * 8192 + bRow];
      bq[0][0] = ds_read128(Bn + sw0);
      bq[0][1] = ds_read128(Bn + sw1);
      bq[1][0] = ds_read128(Bn + 1024 + sw0);
      bq[1][1] = ds_read128(Bn + 1024 + sw1);
    }
    __builtin_amdgcn_s_setprio(1);
    acc[2][0] = mfma16(a[0][0], bc[0][0], acc[2][0]);
    acc[2][0] = mfma16(a[0][1], bc[0][1], acc[2][0]);
    acc[2][1] = mfma16(a[0][0], bc[1][0], acc[2][1]);
    acc[2][1] = mfma16(a[0][1], bc[1][1], acc[2][1]);
    acc[3][0] = mfma16(a[1][0], bc[0][0], acc[3][0]);
    acc[3][0] = mfma16(a[1][1], bc[0][1], acc[3][0]);
    acc[3][1] = mfma16(a[1][0], bc[1][0], acc[3][1]);
    acc[3][1] = mfma16(a[1][1], bc[1][1], acc[3][1]);
    __builtin_amdgcn_s_setprio(0);
  };

  for (int kt = 0; kt < NT; kt += 2) {
    tile_step(kt,     P, Q);
    tile_step(kt + 1, Q, P);
  }

  // epilogue: 16x16 C map; j innermost for write combining.
  float bvv[4];
#pragma unroll
  for (int j = 0; j < 4; ++j) {
    const int col = tileN + wn * 64 + j * 16 + r15;
    bvv[j] = (NBIAS == 1) ? b0[col] : 0.f;
  }
#pragma unroll
  for (int i = 0; i < 4; ++i) {
#pragma unroll
    for (int r = 0; r < 4; ++r) {
      const long long row = tileM + wm * 64 + i * 16 + g * 4 + r;
      OutT* Crow = C + row * ldc + tileN + wn * 64 + r15;
#pragma unroll
      for (int j = 0; j < 4; ++j)
        store_out(Crow + j * 16, acc[i][j][r] * scale + bvv[j]);
    }
  }
}

// ---------------------------------------------------------------------------
// 128^2 kernel — small MT = Wk^T.Wq precompute only (64 blocks).
// ---------------------------------------------------------------------------
template <typename OutT, int NBIAS>
__global__ __launch_bounds__(256) void gemm_bt(
    const bf16_t* __restrict__ A, const bf16_t* __restrict__ B,
    OutT* __restrict__ C,
    const float* __restrict__ b0, const float* __restrict__ b1,
    const float* __restrict__ b2,
    int M, int N, int K, int lda, int ldb, int ldc, float scale,
    long long strideA, long long strideB, long long strideC) {
  const int z = blockIdx.z;
  A += (long long)z * strideA;
  B += (long long)z * strideB;
  C += (long long)z * strideC;

  int bx = blockIdx.x, by = blockIdx.y;
  {
    const int GX  = gridDim.x;
    const int id  = by * GX + bx;
    const int per = GX * 8;
    const int grp = id / per;
    const int rem = id - grp * per;
    by = grp * 8 + (rem & 7);
    bx = rem >> 3;
  }

  __shared__ __align__(16) bf16_t As[BM * BKT];  // 16 KB
  __shared__ __align__(16) bf16_t Bs[BN * BKT];  // 16 KB

  const int t    = threadIdx.x;
  const int lane = t & 63;
  const int w    = t >> 6;
  const int wm   = w & 1;
  const int wn   = w >> 1;
  const int tileM = by * BM;
  const int tileN = bx * BN;

  f32x16 acc[2][2] = {};

  for (int k0 = 0; k0 < K; k0 += BKT) {
#pragma unroll
    for (int i = 0; i < 4; ++i) {
      const int c   = t + 256 * i;
      const int row = c >> 3;
      const int cc  = c & 7;
      const int gcc = cc ^ (row & 7);
      const int ldsbase = ((t & ~63) + 256 * i) * 8;
      async_copy16(A + (long long)(tileM + row) * lda + k0 + gcc * 8, &As[ldsbase]);
      async_copy16(B + (long long)(tileN + row) * ldb + k0 + gcc * 8, &Bs[ldsbase]);
    }
    __syncthreads();

#pragma unroll
    for (int s = 0; s < 4; ++s) {
      const int kc = s + 4 * (lane >> 5);
      bf16x8 af[2], bfr[2];
#pragma unroll
      for (int ti = 0; ti < 2; ++ti) {
        const int row = wm * 64 + ti * 32 + (lane & 31);
        af[ti] = *(const bf16x8*)&As[row * BKT + ((kc ^ (row & 7)) * 8)];
      }
#pragma unroll
      for (int tj = 0; tj < 2; ++tj) {
        const int row = wn * 64 + tj * 32 + (lane & 31);
        bfr[tj] = *(const bf16x8*)&Bs[row * BKT + ((kc ^ (row & 7)) * 8)];
      }
#pragma unroll
      for (int ti = 0; ti < 2; ++ti)
#pragma unroll
        for (int tj = 0; tj < 2; ++tj)
          acc[ti][tj] = __builtin_amdgcn_mfma_f32_32x32x16_bf16(
              af[ti], bfr[tj], acc[ti][tj], 0, 0, 0);
    }
    __syncthreads();
  }

#pragma unroll
  for (int tj = 0; tj < 2; ++tj) {
    const int col = tileN + wn * 64 + tj * 32 + (lane & 31);
    float bv = 0.f;
    if (NBIAS == 1) bv = b0[col];
    if (NBIAS == 3) {
      const float* bp = col < 1024 ? b0 : (col < 2048 ? b1 : b2);
      bv = bp[col & 1023];
    }
#pragma unroll
    for (int ti = 0; ti < 2; ++ti) {
      const int rowb = tileM + wm * 64 + ti * 32 + 4 * (lane >> 5);
#pragma unroll
      for (int r = 0; r < 16; ++r) {
        const int row = rowb + (r & 3) + 8 * (r >> 2);
        store_out(&C[(long long)row * ldc + col], acc[ti][tj][r] * scale + bv);
      }
    }
  }
}

// ---------------------------------------------------------------------------
// fused cast: 4 weights (separate dsts) + x in one dispatch.
// ---------------------------------------------------------------------------
__global__ __launch_bounds__(256) void cast_all(
    const float4* __restrict__ w0, const float4* __restrict__ w1,
    const float4* __restrict__ w2, const float4* __restrict__ w3,
    const float4* __restrict__ x,
    bf16x4* __restrict__ d0, bf16x4* __restrict__ d1,
    bf16x4* __restrict__ d2, bf16x4* __restrict__ d3,
    bf16x4* __restrict__ xdst) {
  const int N4W = 1 << 18;  // 1024*1024/4
  const int id = blockIdx.x * 256 + threadIdx.x;
  const float4* src;
  bf16x4* dst;
  if (id < 4 * N4W) {
    const int z = id >> 18;
    const int i = id & (N4W - 1);
    src = (z == 0 ? w0 : z == 1 ? w1 : z == 2 ? w2 : w3) + i;
    dst = (z == 0 ? d0 : z == 1 ? d1 : z == 2 ? d2 : d3) + i;
  } else {
    const int i = id - 4 * N4W;
    src = x + i;
    dst = xdst + i;
  }
  const float4 v = *src;
  bf16x4 o;
  o[0] = (bf16_t)v.x; o[1] = (bf16_t)v.y; o[2] = (bf16_t)v.z; o[3] = (bf16_t)v.w;
  *dst = o;
}

// ---------------------------------------------------------------------------
// v = bq . Wk via WkT rows: one wave per output column (grid 256 x 4 waves).
// ---------------------------------------------------------------------------
__global__ __launch_bounds__(256) void bias_v(
    const bf16_t* __restrict__ WkT, const float* __restrict__ bq,
    float* __restrict__ v) {
  const int wv   = threadIdx.x >> 6;
  const int lane = threadIdx.x & 63;
  const int j    = blockIdx.x * 4 + wv;  // grid 256 -> j in [0,1024)
  const bf16x8* row = (const bf16x8*)(WkT + (long long)j * 1024);
  float acc = 0.f;
#pragma unroll
  for (int h = 0; h < 2; ++h) {
    const bf16x8 w8 = row[lane * 2 + h];
#pragma unroll
    for (int e = 0; e < 8; ++e)
      acc += (float)w8[e] * bq[lane * 16 + h * 8 + e];
  }
#pragma unroll
  for (int off = 32; off > 0; off >>= 1) acc += __shfl_xor(acc, off);
  if (lane == 0) v[j] = acc;
}

// ---------------------------------------------------------------------------
// bf16 transpose [R,C](ldin) -> [C,R], batched via blockIdx.z
// ---------------------------------------------------------------------------
__global__ __launch_bounds__(256) void transpose_bf16(
    const bf16_t* __restrict__ in, bf16_t* __restrict__ out, int R, int C,
    int ldin, long long sIn, long long sOut) {
  in  += (long long)blockIdx.z * sIn;
  out += (long long)blockIdx.z * sOut;
  __shared__ bf16_t tile[32][33];
  const int tx = threadIdx.x, ty = threadIdx.y;
  const int x = blockIdx.x * 32 + tx;
  const int y0 = blockIdx.y * 32;
#pragma unroll
  for (int j = 0; j < 32; j += 8)
    tile[ty + j][tx] = in[(long long)(y0 + ty + j) * ldin + x];
  __syncthreads();
  const int x2 = y0 + tx;
  const int y2 = blockIdx.x * 32;
#pragma unroll
  for (int j = 0; j < 32; j += 8)
    out[(long long)(y2 + ty + j) * R + x2] = tile[tx][ty + j];
}

// ---------------------------------------------------------------------------
// row softmax: 2048-wide rows, 256 threads x 8 elems
// ---------------------------------------------------------------------------
__global__ __launch_bounds__(256) void softmax_rows(
    const bf16_t* __restrict__ S, bf16_t* __restrict__ P, int cols) {
  const long long row = blockIdx.x;
  const bf16x8* inp = (const bf16x8*)(S + row * cols);
  bf16x8* outp      = (bf16x8*)(P + row * cols);
  const int t = threadIdx.x;
  const int w = t >> 6, lane = t & 63;

  const bf16x8 v = inp[t];
  float f[8];
#pragma unroll
  for (int j = 0; j < 8; ++j) f[j] = (float)v[j];

  float m = f[0];
#pragma unroll
  for (int j = 1; j < 8; ++j) m = fmaxf(m, f[j]);
#pragma unroll
  for (int off = 32; off > 0; off >>= 1) m = fmaxf(m, __shfl_xor(m, off));

  __shared__ float red[8];
  if (lane == 0) red[w] = m;
  __syncthreads();
  m = fmaxf(fmaxf(red[0], red[1]), fmaxf(red[2], red[3]));

  float e[8], sum = 0.f;
#pragma unroll
  for (int j = 0; j < 8; ++j) { e[j] = __expf(f[j] - m); sum += e[j]; }
#pragma unroll
  for (int off = 32; off > 0; off >>= 1) sum += __shfl_xor(sum, off);
  if (lane == 0) red[4 + w] = sum;
  __syncthreads();
  sum = red[4] + red[5] + red[6] + red[7];

  const float inv = 1.f / sum;
  bf16x8 o;
#pragma unroll
  for (int j = 0; j < 8; ++j) o[j] = (bf16_t)(e[j] * inv);
  outp[t] = o;
}

// ---------------------------------------------------------------------------
extern "C" void kernel_launch(void* const* d_in, const int* in_sizes, int n_in,
                              void* d_out, int out_size, void* d_ws, size_t ws_size,
                              hipStream_t stream) {
  const int E = 1024, S = 2048, B = 4;
  const int BS = B * S;  // 8192

  const float* x  = (const float*)d_in[0];
  const float* Wq = (const float*)d_in[1];
  const float* bq = (const float*)d_in[2];
  const float* Wk = (const float*)d_in[3];
  const float* bk = (const float*)d_in[4];
  const float* Wv = (const float*)d_in[5];
  const float* bv = (const float*)d_in[6];
  const float* Wo = (const float*)d_in[7];
  const float* bo = (const float*)d_in[8];
  float* out = (float*)d_out;
  (void)bk; (void)Wk;  // bk algebraically eliminated; Wk used via bf16 copy

  char* w = (char*)d_ws;
  const size_t MB = 1ull << 20;
  bf16_t* Wqb  = (bf16_t*)(w + 0 * MB);           // 2 MB  Wq bf16
  bf16_t* Wkb  = Wqb + E * E;                     // 2 MB  Wk bf16
  bf16_t* Wob  = (bf16_t*)(w + 4 * MB);           // 2 MB
  float*  vb   = (float*)(w + 6 * MB);            // 4 KB  v = bq.Wk
  bf16_t* xb   = (bf16_t*)(w + 8 * MB);           // 16 MB [8192,1024]
  bf16_t* QVb  = (bf16_t*)(w + 24 * MB);          // 32 MB [8192,2048] = [G|V]
  bf16_t* WqTb = (bf16_t*)(w + 56 * MB);          // 2 MB
  bf16_t* WkTb = WqTb + E * E;                    // 2 MB
  bf16_t* Wqv  = (bf16_t*)(w + 60 * MB);          // 4 MB [MT(1024); Wv(1024)]
  bf16_t* Wvb  = Wqv + E * E;                     //   (Wv rows of Wqv)
  bf16_t* VTb  = (bf16_t*)(w + 72 * MB);          // 16 MB [B][1024,2048]
  bf16_t* Sb   = (bf16_t*)(w + 88 * MB);          // 32 MB scores
  bf16_t* Pb   = (bf16_t*)(w + 8 * MB);           // 32 MB (xb dead after scores)
  bf16_t* Ob   = (bf16_t*)(w + 40 * MB);          // 16 MB (QVb[16:32MB] dead)

  // ---- all casts in one dispatch
  {
    const int totalBlocks = ((4 << 18) + (1 << 21)) / 256;  // 12288
    cast_all<<<totalBlocks, 256, 0, stream>>>(
        (const float4*)Wq, (const float4*)Wk, (const float4*)Wv,
        (const float4*)Wo, (const float4*)x,
        (bf16x4*)Wqb, (bf16x4*)Wkb, (bf16x4*)Wvb, (bf16x4*)Wob, (bf16x4*)xb);
  }

  // ---- WqT, WkT (one batched dispatch, z=2)
  transpose_bf16<<<dim3(E / 32, E / 32, 2), dim3(32, 8), 0, stream>>>(
      Wqb, WqTb, E, E, E, (long long)E * E, (long long)E * E);

  // ---- v = bq . Wk = WkT-row dot bq (wave per column)
  bias_v<<<256, 256, 0, stream>>>(WkTb, bq, vb);

  // ---- MT = Wk^T . Wq : gemm_bt(A=WkT, B=WqT) -> Wqv rows 0..1023
  gemm_bt<bf16_t, 0><<<dim3(E / BN, E / BM, 1), 256, 0, stream>>>(
      WkTb, WqTb, Wqv, nullptr, nullptr, nullptr,
      E, E, E, E, E, E, 1.f, 0, 0, 0);

  // ---- fused [G|V] projection: [8192,2048] = xb . Wqv^T + (v|bv)
  gemm256_bt<bf16_t, 3><<<dim3(2 * E / 256, BS / 256, 1), 512, 0, stream>>>(
      xb, Wqv, QVb, vb, bv, bv,
      BS, 2 * E, E, E, E, 2 * E, 1.f, 0, 0, 0);

  // ---- V^T per batch: [2048,1024](ld 2048) -> [1024,2048]
  transpose_bf16<<<dim3(E / 32, S / 32, B), dim3(32, 8), 0, stream>>>(
      QVb + E, VTb, S, E, 2 * E, (long long)S * 2 * E, (long long)E * S);

  // ---- scores' = G . x^T * E^-0.5 per batch
  gemm256_bt<bf16_t, 0><<<dim3(S / 256, S / 256, B), 512, 0, stream>>>(
      QVb, xb, Sb, nullptr, nullptr, nullptr,
      S, S, E, 2 * E, E, S, 0.03125f,
      (long long)S * 2 * E, (long long)S * E, (long long)S * S);

  // ---- softmax
  softmax_rows<<<BS, 256, 0, stream>>>(Sb, Pb, S);

  // ---- O = P . (V^T)^T per batch  (128^2 tile, 2 blocks/CU, 512 blocks)
  gemm128_bt2<bf16_t, 0><<<dim3(E / 128, S / 128, B), 256, 0, stream>>>(
      Pb, VTb, Ob, nullptr,
      S, E, S, S, S, E, 1.f,
      (long long)S * S, (long long)E * S, (long long)S * E);

  // ---- y = O . Wo^T + bo  (128^2 tile, 2 blocks/CU, 512 blocks)
  gemm128_bt2<float, 1><<<dim3(E / 128, BS / 128, 1), 256, 0, stream>>>(
      Ob, Wob, out, bo,
      BS, E, E, E, E, E, 1.f, 0, 0, 0);
}

// Round 11
// 273.818 us; speedup vs baseline: 1.3732x; 1.0279x over previous
//
#include <hip/hip_runtime.h>
#include <hip/hip_bf16.h>

// ---------------------------------------------------------------------------
// SelfAttentionHybrid: single-head attention, B=4 S=2048 E=1024, fp32 in/out.
// R17: budget audit showed ~82us of the timed loop is harness workspace
// re-poison fills (2x fillBufferAligned, 268MB @6.5TB/s) -- fixed cost.
// Remaining kernels ~180us, largest = scores (40.4us, 1 block/CU cold-stream
// stall class). Changes:
//  (a) scores -> gemm128_bt2 (2 blocks/CU TLP, the R16 PV lesson): grid
//      (16,16,4)=1024 blocks; PV-measured rate predicts ~35us.
//  (b) MT = Wk^T.Wq split-K=2 via gemm128_bt2 z-batching (z=k-chunk through
//      strideA/B=512, strideC=1M f32 partials; 128 blocks vs 64) + tiny
//      f32-add+cast combine kernel. ~11us -> ~7.5us.
// Algebra (R13, verified): softmax shift-invariance =>
//   S = q.k^T == x.M.x^T + v.x^T (+row-const), M = Wq^T.Wk, v = bq.Wk.
// ---------------------------------------------------------------------------

typedef __bf16 bf16_t;
typedef __bf16 bf16x8 __attribute__((ext_vector_type(8)));
typedef __bf16 bf16x4 __attribute__((ext_vector_type(4)));
typedef float  f32x16 __attribute__((ext_vector_type(16)));
typedef float  f32x4  __attribute__((ext_vector_type(4)));

__device__ __forceinline__ void async_copy16(const void* g, void* l) {
  __builtin_amdgcn_global_load_lds(
      (const __attribute__((address_space(1))) void*)g,
      (__attribute__((address_space(3))) void*)l, 16, 0, 0);
}

// raw workgroup barrier: NO vmcnt/lgkmcnt drain (unlike __syncthreads).
__device__ __forceinline__ void wg_barrier() {
  asm volatile("" ::: "memory");
  __builtin_amdgcn_s_barrier();
  asm volatile("" ::: "memory");
}

// counted LDS wait + rule-18 scheduler pin (MFMAs must not hoist above it)
#define LGKM(n)                                                  \
  do {                                                           \
    asm volatile("s_waitcnt lgkmcnt(" #n ")" ::: "memory");      \
    __builtin_amdgcn_sched_barrier(0);                           \
  } while (0)

#define VM(n) asm volatile("s_waitcnt vmcnt(" #n ")" ::: "memory")

// 32-bit LDS byte address (for asm ds_read; invisible to alias analysis)
__device__ __forceinline__ unsigned lds_addr(const void* p) {
  return (unsigned)(unsigned long long)(__attribute__((address_space(3))) const void*)p;
}

// inline-asm LDS read: compiler cannot see this as an LDS access, so it does
// NOT insert vmcnt(0) ordering vs in-flight global_load_lds prefetches.
// Ordering enforced manually via LGKM() + the per-tile vmcnt/barrier.
__device__ __forceinline__ bf16x8 ds_read128(const bf16_t* p) {
  bf16x8 r;
  asm volatile("ds_read_b128 %0, %1" : "=v"(r) : "v"(lds_addr(p)));
  return r;
}

__device__ __forceinline__ f32x4 mfma16(bf16x8 a, bf16x8 b, f32x4 c) {
  return __builtin_amdgcn_mfma_f32_16x16x32_bf16(a, b, c, 0, 0, 0);
}

__device__ __forceinline__ void store_out(float* p, float v)  { *p = v; }
__device__ __forceinline__ void store_out(bf16_t* p, float v) { *p = (bf16_t)v; }

// 4 MFMA: a[i] x bb -> acc[ro+i][co..co+1], both k-slices
#define G_AQ(i, ro, bb, co)                                                   \
  acc[(ro) + (i)][(co) + 0] = mfma16(a[i][0], bb[0][0], acc[(ro) + (i)][(co) + 0]); \
  acc[(ro) + (i)][(co) + 1] = mfma16(a[i][0], bb[1][0], acc[(ro) + (i)][(co) + 1]); \
  acc[(ro) + (i)][(co) + 0] = mfma16(a[i][1], bb[0][1], acc[(ro) + (i)][(co) + 0]); \
  acc[(ro) + (i)][(co) + 1] = mfma16(a[i][1], bb[1][1], acc[(ro) + (i)][(co) + 1]);

// 8 MFMA: all a[i] x bb[j] -> acc[0..3][co+j], both k-slices
#define G_BQ(j, bb, co)                                              \
  acc[0][(co) + (j)] = mfma16(a[0][0], bb[j][0], acc[0][(co) + (j)]); \
  acc[1][(co) + (j)] = mfma16(a[1][0], bb[j][0], acc[1][(co) + (j)]); \
  acc[2][(co) + (j)] = mfma16(a[2][0], bb[j][0], acc[2][(co) + (j)]); \
  acc[3][(co) + (j)] = mfma16(a[3][0], bb[j][0], acc[3][(co) + (j)]); \
  acc[0][(co) + (j)] = mfma16(a[0][1], bb[j][1], acc[0][(co) + (j)]); \
  acc[1][(co) + (j)] = mfma16(a[1][1], bb[j][1], acc[1][(co) + (j)]); \
  acc[2][(co) + (j)] = mfma16(a[2][1], bb[j][1], acc[2][(co) + (j)]); \
  acc[3][(co) + (j)] = mfma16(a[3][1], bb[j][1], acc[3][(co) + (j)]);

// ---------------------------------------------------------------------------
// gemm256_bt (R10 config): C[M,N] = A[M,K](lda) x B[N,K](ldb)^T * scale + b.
// 512 thr = 8 waves (2Mx4N); wave tile 128x64 = 8x4 frags of 16x16x32 MFMA.
// LDS [2 buf][256 rows][64 bf16] per matrix; slot (r,cc) holds global chunk
// cc^(r&7); reads use slot kc^(r&7) (involution; 16-row instrs => 2-way max,
// measured 0 conflicts). Used for the L2-hot QV projection.
// Requires M%256==0, N%256==0, K%128==0 (NT even), gridDim.y%8==0.
// ---------------------------------------------------------------------------
template <typename OutT, int NBIAS>
__global__ __launch_bounds__(512, 2) void gemm256_bt(
    const bf16_t* __restrict__ A, const bf16_t* __restrict__ B,
    OutT* __restrict__ C,
    const float* __restrict__ b0, const float* __restrict__ b1,
    const float* __restrict__ b2,
    int M, int N, int K, int lda, int ldb, int ldc, float scale,
    long long strideA, long long strideB, long long strideC) {
  const int z = blockIdx.z;
  A += (long long)z * strideA;
  B += (long long)z * strideB;
  C += (long long)z * strideC;

  // L2 supertile remap: 8 y-tiles per supertile, y-fastest inside.
  int bx = blockIdx.x, by = blockIdx.y;
  {
    const int GX  = gridDim.x;
    const int id  = by * GX + bx;
    const int per = GX * 8;
    const int grp = id / per;
    const int rem = id - grp * per;
    by = grp * 8 + (rem & 7);
    bx = rem >> 3;
  }

  __shared__ __align__(16) bf16_t As[2 * 256 * 64];  // 64 KB
  __shared__ __align__(16) bf16_t Bs[2 * 256 * 64];  // 64 KB

  const int t    = threadIdx.x;
  const int lane = t & 63;
  const int w    = t >> 6;
  const int wm   = w & 1;    // M-half of output tile
  const int wn   = w >> 1;   // N-quarter of output tile
  const int g    = lane >> 4;
  const int l7   = lane & 7;
  const int r15  = lane & 15;
  const int tileM = by * 256;
  const int tileN = bx * 256;

  // staging constants: thread covers chunks t and t+512 of each half-tile
  const int row0 = t >> 3;                    // 0..63
  const int gcc  = (t & 7) ^ (row0 & 7);      // swizzled source chunk
  const int dstb = (t & ~63) * 8;             // wave-uniform LDS base (elems)

  // read constants
  const int sw0 = ((0 + g) ^ l7) * 8;         // k-slice 0 chunk offset (elems)
  const int sw1 = ((4 + g) ^ l7) * 8;         // k-slice 1
  const int aRow = (wm * 128 + r15) * 64;
  const int bRow = (wn * 64 + r15) * 64;

  const int NT = K >> 6;

  f32x4 acc[8][4] = {};

  auto stageA = [&](int kt, int h) {
    const int cb = (kt & 1) * 16384;
    const bf16_t* src =
        A + (long long)(tileM + h * 128 + row0) * lda + kt * 64 + gcc * 8;
    bf16_t* dst = &As[cb + h * 8192 + dstb];
    async_copy16(src, dst);
    async_copy16(src + (long long)64 * lda, dst + 4096);
  };
  auto stageB = [&](int kt, int h) {
    const int cb = (kt & 1) * 16384;
    const bf16_t* src =
        B + (long long)(tileN + h * 128 + row0) * ldb + kt * 64 + gcc * 8;
    bf16_t* dst = &Bs[cb + h * 8192 + dstb];
    async_copy16(src, dst);
    async_copy16(src + (long long)64 * ldb, dst + 4096);
  };

  // prologue: stage tile 0 only; retire; pre-read B0(0) (4 reads stay
  // outstanding into tile 0 ph0 -- steady-state invariant).
  stageA(0, 0); stageA(0, 1); stageB(0, 0); stageB(0, 1);
  VM(0);
  wg_barrier();

  bf16x8 a[4][2], P[2][2], Q[2][2];
#pragma unroll
  for (int j = 0; j < 2; ++j) {
    P[j][0] = ds_read128(&Bs[bRow + j * 1024 + sw0]);
    P[j][1] = ds_read128(&Bs[bRow + j * 1024 + sw1]);
  }

  // bc = B0(kt) (read at prev ph3); bq = scratch: gets B1(kt) then B0(kt+1)
  auto tile_step = [&](int kt, bf16x8 (&bc)[2][2], bf16x8 (&bq)[2][2]) {
    const int cb = (kt & 1) * 16384;
    const int kn = kt + 1;
    const bf16_t* Ab = &As[cb + aRow];
    const bf16_t* Bb = &Bs[cb + bRow];

    // ---- ph0: issue A0 reads (outstanding 4+8=12); stage B(kt+1);
    //           MFMA M0N0 interleaved on counted lgkm.
#pragma unroll
    for (int i = 0; i < 4; ++i) {
      a[i][0] = ds_read128(Ab + i * 1024 + sw0);
      a[i][1] = ds_read128(Ab + i * 1024 + sw1);
    }
    if (kn < NT) { stageB(kn, 0); stageB(kn, 1); }
    __builtin_amdgcn_s_setprio(1);
    LGKM(6);  // retires B0(kt) x4 + a[0] pair
    G_AQ(0, 0, bc, 0)
    LGKM(4);
    G_AQ(1, 0, bc, 0)
    LGKM(2);
    G_AQ(2, 0, bc, 0)
    LGKM(0);
    G_AQ(3, 0, bc, 0)
    __builtin_amdgcn_s_setprio(0);

    // ---- ph1: issue B1 reads (4); stage A(kt+1); MFMA M0N1 interleaved.
#pragma unroll
    for (int j = 0; j < 2; ++j) {
      bq[j][0] = ds_read128(Bb + 2048 + j * 1024 + sw0);
      bq[j][1] = ds_read128(Bb + 2048 + j * 1024 + sw1);
    }
    if (kn < NT) { stageA(kn, 0); stageA(kn, 1); }
    __builtin_amdgcn_s_setprio(1);
    LGKM(2);  // bq[0] ready
    G_BQ(0, bq, 2)
    LGKM(0);  // bq[1] ready
    G_BQ(1, bq, 2)
    __builtin_amdgcn_s_setprio(0);

    // ---- ph2: issue A1 reads (8); MFMA M1N1 interleaved; then retire
    //           staging(kt+1) [exact: only those 8 in flight] + barrier.
#pragma unroll
    for (int i = 0; i < 4; ++i) {
      a[i][0] = ds_read128(Ab + 4096 + i * 1024 + sw0);
      a[i][1] = ds_read128(Ab + 4096 + i * 1024 + sw1);
    }
    __builtin_amdgcn_s_setprio(1);
    LGKM(6);
    G_AQ(0, 4, bq, 2)
    LGKM(4);
    G_AQ(1, 4, bq, 2)
    LGKM(2);
    G_AQ(2, 4, bq, 2)
    LGKM(0);
    G_AQ(3, 4, bq, 2)
    __builtin_amdgcn_s_setprio(0);
    VM(0);
    wg_barrier();  // buffer (kt+1)&1 now visible to all waves

    // ---- ph3: read B0(kt+1) -> bq (B1 dead; drains under next ph0's
    //           LGKM(6)); MFMA M1N0 -- all inputs resident, no wait.
    if (kn < NT) {
      const bf16_t* Bn = &Bs[(kn & 1) * 16384 + bRow];
#pragma unroll
      for (int j = 0; j < 2; ++j) {
        bq[j][0] = ds_read128(Bn + j * 1024 + sw0);
        bq[j][1] = ds_read128(Bn + j * 1024 + sw1);
      }
    }
    __builtin_amdgcn_s_setprio(1);
    G_AQ(0, 4, bc, 0)
    G_AQ(1, 4, bc, 0)
    G_AQ(2, 4, bc, 0)
    G_AQ(3, 4, bc, 0)
    __builtin_amdgcn_s_setprio(0);
  };

  for (int kt = 0; kt < NT; kt += 2) {
    tile_step(kt,     P, Q);   // bc = P holds B0(kt);   Q gets B1, B0(kt+1)
    tile_step(kt + 1, Q, P);   // bc = Q holds B0(kt+1); P gets B1, B0(kt+2)
  }

  // epilogue: 16x16 C map: col = lane&15, row = (lane>>4)*4 + r.
  // j innermost: 4 consecutive 32B segments per row -> 128B write-combining.
  float bvv[4];
#pragma unroll
  for (int j = 0; j < 4; ++j) {
    const int col = tileN + wn * 64 + j * 16 + r15;
    float bv = 0.f;
    if (NBIAS == 1) bv = b0[col];
    if (NBIAS == 3) {
      const float* bp = col < 1024 ? b0 : (col < 2048 ? b1 : b2);
      bv = bp[col & 1023];
    }
    bvv[j] = bv;
  }
#pragma unroll
  for (int i = 0; i < 8; ++i) {
#pragma unroll
    for (int r = 0; r < 4; ++r) {
      const long long row = tileM + wm * 128 + i * 16 + g * 4 + r;
      OutT* Crow = C + row * ldc + tileN + wn * 64 + r15;
#pragma unroll
      for (int j = 0; j < 4; ++j)
        store_out(Crow + j * 16, acc[i][j][r] * scale + bvv[j]);
    }
  }
}

// ---------------------------------------------------------------------------
// gemm128_bt2: 128x128 tile, 256 thr / 4 waves (2Mx2N), wave tile 64x64 =
// 4x4 frags of 16x16x32. LDS 2buf 64KB -> 2 blocks/CU (cross-block TLP
// hides the per-tile VM(0)+barrier drain -- the R15/R16 lesson). Counted-lgkm
// ladder, 1 barrier/tile, exact VM(0). Conflict-free 16-row reads.
// Per-wave/K-tile: 16 ds_read_b128, 32 MFMA.
// Used for: scores, PV, out-proj, MT split-K partials.
// Requires M%128==0, N%128==0, K%128==0 (NT even), gridDim.y%8==0.
// ---------------------------------------------------------------------------
template <typename OutT, int NBIAS>
__global__ __launch_bounds__(256, 2) void gemm128_bt2(
    const bf16_t* __restrict__ A, const bf16_t* __restrict__ B,
    OutT* __restrict__ C,
    const float* __restrict__ b0,
    int M, int N, int K, int lda, int ldb, int ldc, float scale,
    long long strideA, long long strideB, long long strideC) {
  const int z = blockIdx.z;
  A += (long long)z * strideA;
  B += (long long)z * strideB;
  C += (long long)z * strideC;

  // L2 supertile remap: 8 y-tiles per supertile, y-fastest inside.
  int bx = blockIdx.x, by = blockIdx.y;
  {
    const int GX  = gridDim.x;
    const int id  = by * GX + bx;
    const int per = GX * 8;
    const int grp = id / per;
    const int rem = id - grp * per;
    by = grp * 8 + (rem & 7);
    bx = rem >> 3;
  }

  __shared__ __align__(16) bf16_t As[2 * 128 * 64];  // 32 KB
  __shared__ __align__(16) bf16_t Bs[2 * 128 * 64];  // 32 KB

  const int t    = threadIdx.x;
  const int lane = t & 63;
  const int w    = t >> 6;
  const int wm   = w & 1;    // M half (64 rows)
  const int wn   = w >> 1;   // N half (64 cols)
  const int g    = lane >> 4;
  const int l7   = lane & 7;
  const int r15  = lane & 15;
  const int tileM = by * 128;
  const int tileN = bx * 128;

  const int sw0 = ((0 + g) ^ l7) * 8;
  const int sw1 = ((4 + g) ^ l7) * 8;
  const int aRow = (wm * 64 + r15) * 64;
  const int bRow = (wn * 64 + r15) * 64;

  const int NT = K >> 6;

  f32x4 acc[4][4] = {};

  auto stageA = [&](int kt) {
    const int cb = (kt & 1) * 8192;
#pragma unroll
    for (int i = 0; i < 4; ++i) {
      const int c   = t + 256 * i;
      const int row = c >> 3;
      const int cc  = c & 7;
      const int gcc = cc ^ (row & 7);
      const int ldsbase = ((t & ~63) + 256 * i) * 8;
      async_copy16(A + (long long)(tileM + row) * lda + kt * 64 + gcc * 8,
                   &As[cb + ldsbase]);
    }
  };
  auto stageB = [&](int kt) {
    const int cb = (kt & 1) * 8192;
#pragma unroll
    for (int i = 0; i < 4; ++i) {
      const int c   = t + 256 * i;
      const int row = c >> 3;
      const int cc  = c & 7;
      const int gcc = cc ^ (row & 7);
      const int ldsbase = ((t & ~63) + 256 * i) * 8;
      async_copy16(B + (long long)(tileN + row) * ldb + kt * 64 + gcc * 8,
                   &Bs[cb + ldsbase]);
    }
  };

  // prologue: stage tile 0 (8 copies); retire; pre-read B0(0) (4 reads stay
  // outstanding into tile 0 ph0).
  stageA(0); stageB(0);
  VM(0);
  wg_barrier();

  bf16x8 a[2][2], P[2][2], Q[2][2];
#pragma unroll
  for (int j = 0; j < 2; ++j) {
    P[j][0] = ds_read128(&Bs[bRow + j * 1024 + sw0]);
    P[j][1] = ds_read128(&Bs[bRow + j * 1024 + sw1]);
  }

  // bc = B0(kt) [N-frags 0,1] read at prev ph3; bq = scratch (B1, B0-next).
  auto tile_step = [&](int kt, bf16x8 (&bc)[2][2], bf16x8 (&bq)[2][2]) {
    const int cb = (kt & 1) * 8192;
    const int kn = kt + 1;
    const bf16_t* Ab = &As[cb + aRow];
    const bf16_t* Bb = &Bs[cb + bRow];

    // ---- ph0: issue 4 A0 reads (outstanding 4+4=8); stage B(kt+1);
    //           MFMA M0,M1 x N0,N1 (bc) on counted lgkm.
    a[0][0] = ds_read128(Ab + sw0);
    a[0][1] = ds_read128(Ab + sw1);
    a[1][0] = ds_read128(Ab + 1024 + sw0);
    a[1][1] = ds_read128(Ab + 1024 + sw1);
    if (kn < NT) stageB(kn);
    __builtin_amdgcn_s_setprio(1);
    LGKM(3);  // retires bc x4 + a[0][0]
    acc[0][0] = mfma16(a[0][0], bc[0][0], acc[0][0]);
    acc[0][1] = mfma16(a[0][0], bc[1][0], acc[0][1]);
    LGKM(2);
    acc[0][0] = mfma16(a[0][1], bc[0][1], acc[0][0]);
    acc[0][1] = mfma16(a[0][1], bc[1][1], acc[0][1]);
    LGKM(1);
    acc[1][0] = mfma16(a[1][0], bc[0][0], acc[1][0]);
    acc[1][1] = mfma16(a[1][0], bc[1][0], acc[1][1]);
    LGKM(0);
    acc[1][0] = mfma16(a[1][1], bc[0][1], acc[1][0]);
    acc[1][1] = mfma16(a[1][1], bc[1][1], acc[1][1]);
    __builtin_amdgcn_s_setprio(0);

    // ---- ph1: issue 4 B1 reads -> bq; stage A(kt+1); MFMA M0,M1 x N2,N3.
    bq[0][0] = ds_read128(Bb + 2048 + sw0);
    bq[0][1] = ds_read128(Bb + 2048 + sw1);
    bq[1][0] = ds_read128(Bb + 3072 + sw0);
    bq[1][1] = ds_read128(Bb + 3072 + sw1);
    if (kn < NT) stageA(kn);
    __builtin_amdgcn_s_setprio(1);
    LGKM(3);
    acc[0][2] = mfma16(a[0][0], bq[0][0], acc[0][2]);
    acc[1][2] = mfma16(a[1][0], bq[0][0], acc[1][2]);
    LGKM(2);
    acc[0][2] = mfma16(a[0][1], bq[0][1], acc[0][2]);
    acc[1][2] = mfma16(a[1][1], bq[0][1], acc[1][2]);
    LGKM(1);
    acc[0][3] = mfma16(a[0][0], bq[1][0], acc[0][3]);
    acc[1][3] = mfma16(a[1][0], bq[1][0], acc[1][3]);
    LGKM(0);
    acc[0][3] = mfma16(a[0][1], bq[1][1], acc[0][3]);
    acc[1][3] = mfma16(a[1][1], bq[1][1], acc[1][3]);
    __builtin_amdgcn_s_setprio(0);

    // ---- ph2: issue 4 A1 reads (frags M2,M3); MFMA M2,M3 x N2,N3 (bq);
    //           exact VM(0) [8 staging copies in flight]; barrier.
    a[0][0] = ds_read128(Ab + 2048 + sw0);
    a[0][1] = ds_read128(Ab + 2048 + sw1);
    a[1][0] = ds_read128(Ab + 3072 + sw0);
    a[1][1] = ds_read128(Ab + 3072 + sw1);
    __builtin_amdgcn_s_setprio(1);
    LGKM(3);
    acc[2][2] = mfma16(a[0][0], bq[0][0], acc[2][2]);
    acc[2][3] = mfma16(a[0][0], bq[1][0], acc[2][3]);
    LGKM(2);
    acc[2][2] = mfma16(a[0][1], bq[0][1], acc[2][2]);
    acc[2][3] = mfma16(a[0][1], bq[1][1], acc[2][3]);
    LGKM(1);
    acc[3][2] = mfma16(a[1][0], bq[0][0], acc[3][2]);
    acc[3][3] = mfma16(a[1][0], bq[1][0], acc[3][3]);
    LGKM(0);
    acc[3][2] = mfma16(a[1][1], bq[0][1], acc[3][2]);
    acc[3][3] = mfma16(a[1][1], bq[1][1], acc[3][3]);
    __builtin_amdgcn_s_setprio(0);
    VM(0);
    wg_barrier();  // buffer (kt+1)&1 now visible to all waves

    // ---- ph3: read B0(kt+1) -> bq (B1 dead; drains under next ph0's
    //           LGKM(3)); MFMA M2,M3 x N0,N1 (bc) reg-only.
    if (kn < NT) {
      const bf16_t* Bn = &Bs[(kn & 1) * 8192 + bRow];
      bq[0][0] = ds_read128(Bn + sw0);
      bq[0][1] = ds_read128(Bn + sw1);
      bq[1][0] = ds_read128(Bn + 1024 + sw0);
      bq[1][1] = ds_read128(Bn + 1024 + sw1);
    }
    __builtin_amdgcn_s_setprio(1);
    acc[2][0] = mfma16(a[0][0], bc[0][0], acc[2][0]);
    acc[2][0] = mfma16(a[0][1], bc[0][1], acc[2][0]);
    acc[2][1] = mfma16(a[0][0], bc[1][0], acc[2][1]);
    acc[2][1] = mfma16(a[0][1], bc[1][1], acc[2][1]);
    acc[3][0] = mfma16(a[1][0], bc[0][0], acc[3][0]);
    acc[3][0] = mfma16(a[1][1], bc[0][1], acc[3][0]);
    acc[3][1] = mfma16(a[1][0], bc[1][0], acc[3][1]);
    acc[3][1] = mfma16(a[1][1], bc[1][1], acc[3][1]);
    __builtin_amdgcn_s_setprio(0);
  };

  for (int kt = 0; kt < NT; kt += 2) {
    tile_step(kt,     P, Q);
    tile_step(kt + 1, Q, P);
  }

  // epilogue: 16x16 C map; j innermost for write combining.
  float bvv[4];
#pragma unroll
  for (int j = 0; j < 4; ++j) {
    const int col = tileN + wn * 64 + j * 16 + r15;
    bvv[j] = (NBIAS == 1) ? b0[col] : 0.f;
  }
#pragma unroll
  for (int i = 0; i < 4; ++i) {
#pragma unroll
    for (int r = 0; r < 4; ++r) {
      const long long row = tileM + wm * 64 + i * 16 + g * 4 + r;
      OutT* Crow = C + row * ldc + tileN + wn * 64 + r15;
#pragma unroll
      for (int j = 0; j < 4; ++j)
        store_out(Crow + j * 16, acc[i][j][r] * scale + bvv[j]);
    }
  }
}

// ---------------------------------------------------------------------------
// combine_mt: Wqv[i] = bf16(p0[i] + p1[i]) -- split-K reduction of the MT
// precompute. 1M elems, 4/thread, 1024 blocks.
// ---------------------------------------------------------------------------
__global__ __launch_bounds__(256) void combine_mt(
    const float4* __restrict__ p0, const float4* __restrict__ p1,
    bf16x4* __restrict__ o) {
  const int id = blockIdx.x * 256 + threadIdx.x;
  const float4 a = p0[id], b = p1[id];
  bf16x4 r;
  r[0] = (bf16_t)(a.x + b.x); r[1] = (bf16_t)(a.y + b.y);
  r[2] = (bf16_t)(a.z + b.z); r[3] = (bf16_t)(a.w + b.w);
  o[id] = r;
}

// ---------------------------------------------------------------------------
// fused cast: 4 weights (separate dsts) + x in one dispatch.
// ---------------------------------------------------------------------------
__global__ __launch_bounds__(256) void cast_all(
    const float4* __restrict__ w0, const float4* __restrict__ w1,
    const float4* __restrict__ w2, const float4* __restrict__ w3,
    const float4* __restrict__ x,
    bf16x4* __restrict__ d0, bf16x4* __restrict__ d1,
    bf16x4* __restrict__ d2, bf16x4* __restrict__ d3,
    bf16x4* __restrict__ xdst) {
  const int N4W = 1 << 18;  // 1024*1024/4
  const int id = blockIdx.x * 256 + threadIdx.x;
  const float4* src;
  bf16x4* dst;
  if (id < 4 * N4W) {
    const int z = id >> 18;
    const int i = id & (N4W - 1);
    src = (z == 0 ? w0 : z == 1 ? w1 : z == 2 ? w2 : w3) + i;
    dst = (z == 0 ? d0 : z == 1 ? d1 : z == 2 ? d2 : d3) + i;
  } else {
    const int i = id - 4 * N4W;
    src = x + i;
    dst = xdst + i;
  }
  const float4 v = *src;
  bf16x4 o;
  o[0] = (bf16_t)v.x; o[1] = (bf16_t)v.y; o[2] = (bf16_t)v.z; o[3] = (bf16_t)v.w;
  *dst = o;
}

// ---------------------------------------------------------------------------
// v = bq . Wk via WkT rows: one wave per output column (grid 256 x 4 waves).
// ---------------------------------------------------------------------------
__global__ __launch_bounds__(256) void bias_v(
    const bf16_t* __restrict__ WkT, const float* __restrict__ bq,
    float* __restrict__ v) {
  const int wv   = threadIdx.x >> 6;
  const int lane = threadIdx.x & 63;
  const int j    = blockIdx.x * 4 + wv;  // grid 256 -> j in [0,1024)
  const bf16x8* row = (const bf16x8*)(WkT + (long long)j * 1024);
  float acc = 0.f;
#pragma unroll
  for (int h = 0; h < 2; ++h) {
    const bf16x8 w8 = row[lane * 2 + h];
#pragma unroll
    for (int e = 0; e < 8; ++e)
      acc += (float)w8[e] * bq[lane * 16 + h * 8 + e];
  }
#pragma unroll
  for (int off = 32; off > 0; off >>= 1) acc += __shfl_xor(acc, off);
  if (lane == 0) v[j] = acc;
}

// ---------------------------------------------------------------------------
// bf16 transpose [R,C](ldin) -> [C,R], batched via blockIdx.z
// ---------------------------------------------------------------------------
__global__ __launch_bounds__(256) void transpose_bf16(
    const bf16_t* __restrict__ in, bf16_t* __restrict__ out, int R, int C,
    int ldin, long long sIn, long long sOut) {
  in  += (long long)blockIdx.z * sIn;
  out += (long long)blockIdx.z * sOut;
  __shared__ bf16_t tile[32][33];
  const int tx = threadIdx.x, ty = threadIdx.y;
  const int x = blockIdx.x * 32 + tx;
  const int y0 = blockIdx.y * 32;
#pragma unroll
  for (int j = 0; j < 32; j += 8)
    tile[ty + j][tx] = in[(long long)(y0 + ty + j) * ldin + x];
  __syncthreads();
  const int x2 = y0 + tx;
  const int y2 = blockIdx.x * 32;
#pragma unroll
  for (int j = 0; j < 32; j += 8)
    out[(long long)(y2 + ty + j) * R + x2] = tile[tx][ty + j];
}

// ---------------------------------------------------------------------------
// row softmax: 2048-wide rows, 256 threads x 8 elems
// ---------------------------------------------------------------------------
__global__ __launch_bounds__(256) void softmax_rows(
    const bf16_t* __restrict__ S, bf16_t* __restrict__ P, int cols) {
  const long long row = blockIdx.x;
  const bf16x8* inp = (const bf16x8*)(S + row * cols);
  bf16x8* outp      = (bf16x8*)(P + row * cols);
  const int t = threadIdx.x;
  const int w = t >> 6, lane = t & 63;

  const bf16x8 v = inp[t];
  float f[8];
#pragma unroll
  for (int j = 0; j < 8; ++j) f[j] = (float)v[j];

  float m = f[0];
#pragma unroll
  for (int j = 1; j < 8; ++j) m = fmaxf(m, f[j]);
#pragma unroll
  for (int off = 32; off > 0; off >>= 1) m = fmaxf(m, __shfl_xor(m, off));

  __shared__ float red[8];
  if (lane == 0) red[w] = m;
  __syncthreads();
  m = fmaxf(fmaxf(red[0], red[1]), fmaxf(red[2], red[3]));

  float e[8], sum = 0.f;
#pragma unroll
  for (int j = 0; j < 8; ++j) { e[j] = __expf(f[j] - m); sum += e[j]; }
#pragma unroll
  for (int off = 32; off > 0; off >>= 1) sum += __shfl_xor(sum, off);
  if (lane == 0) red[4 + w] = sum;
  __syncthreads();
  sum = red[4] + red[5] + red[6] + red[7];

  const float inv = 1.f / sum;
  bf16x8 o;
#pragma unroll
  for (int j = 0; j < 8; ++j) o[j] = (bf16_t)(e[j] * inv);
  outp[t] = o;
}

// ---------------------------------------------------------------------------
extern "C" void kernel_launch(void* const* d_in, const int* in_sizes, int n_in,
                              void* d_out, int out_size, void* d_ws, size_t ws_size,
                              hipStream_t stream) {
  const int E = 1024, S = 2048, B = 4;
  const int BS = B * S;  // 8192

  const float* x  = (const float*)d_in[0];
  const float* Wq = (const float*)d_in[1];
  const float* bq = (const float*)d_in[2];
  const float* Wk = (const float*)d_in[3];
  const float* bk = (const float*)d_in[4];
  const float* Wv = (const float*)d_in[5];
  const float* bv = (const float*)d_in[6];
  const float* Wo = (const float*)d_in[7];
  const float* bo = (const float*)d_in[8];
  float* out = (float*)d_out;
  (void)bk; (void)Wk;  // bk algebraically eliminated; Wk used via bf16 copy

  char* w = (char*)d_ws;
  const size_t MB = 1ull << 20;
  bf16_t* Wqb  = (bf16_t*)(w + 0 * MB);           // 2 MB  Wq bf16
  bf16_t* Wkb  = Wqb + E * E;                     // 2 MB  Wk bf16
  bf16_t* Wob  = (bf16_t*)(w + 4 * MB);           // 2 MB
  float*  vb   = (float*)(w + 6 * MB);            // 4 KB  v = bq.Wk
  bf16_t* xb   = (bf16_t*)(w + 8 * MB);           // 16 MB [8192,1024]
  bf16_t* QVb  = (bf16_t*)(w + 24 * MB);          // 32 MB [8192,2048] = [G|V]
  bf16_t* WqTb = (bf16_t*)(w + 56 * MB);          // 2 MB
  bf16_t* WkTb = WqTb + E * E;                    // 2 MB
  bf16_t* Wqv  = (bf16_t*)(w + 60 * MB);          // 4 MB [MT(1024); Wv(1024)]
  bf16_t* Wvb  = Wqv + E * E;                     //   (Wv rows of Wqv)
  bf16_t* VTb  = (bf16_t*)(w + 72 * MB);          // 16 MB [B][1024,2048]
  bf16_t* Sb   = (bf16_t*)(w + 88 * MB);          // 32 MB scores
  bf16_t* Pb   = (bf16_t*)(w + 8 * MB);           // 32 MB (xb dead after scores)
  bf16_t* Ob   = (bf16_t*)(w + 40 * MB);          // 16 MB (QVb[16:32MB] dead)
  float*  MTf  = (float*)(w + 120 * MB);          // 8 MB  split-K f32 partials

  // ---- all casts in one dispatch
  {
    const int totalBlocks = ((4 << 18) + (1 << 21)) / 256;  // 12288
    cast_all<<<totalBlocks, 256, 0, stream>>>(
        (const float4*)Wq, (const float4*)Wk, (const float4*)Wv,
        (const float4*)Wo, (const float4*)x,
        (bf16x4*)Wqb, (bf16x4*)Wkb, (bf16x4*)Wvb, (bf16x4*)Wob, (bf16x4*)xb);
  }

  // ---- WqT, WkT (one batched dispatch, z=2)
  transpose_bf16<<<dim3(E / 32, E / 32, 2), dim3(32, 8), 0, stream>>>(
      Wqb, WqTb, E, E, E, (long long)E * E, (long long)E * E);

  // ---- v = bq . Wk = WkT-row dot bq (wave per column)
  bias_v<<<256, 256, 0, stream>>>(WkTb, bq, vb);

  // ---- MT = Wk^T . Wq, split-K=2 via z-batching: z picks k-chunk through
  //      strideA/B = 512 (column offset), strideC = 1M f32 (partial buffer).
  gemm128_bt2<float, 0><<<dim3(E / 128, E / 128, 2), 256, 0, stream>>>(
      WkTb, WqTb, MTf, nullptr,
      E, E, 512, E, E, E, 1.f, 512, 512, (long long)E * E);

  // ---- combine partials -> Wqv rows 0..1023 (bf16)
  combine_mt<<<(E * E / 4) / 256, 256, 0, stream>>>(
      (const float4*)MTf, (const float4*)(MTf + E * E), (bf16x4*)Wqv);

  // ---- fused [G|V] projection: [8192,2048] = xb . Wqv^T + (v|bv)
  gemm256_bt<bf16_t, 3><<<dim3(2 * E / 256, BS / 256, 1), 512, 0, stream>>>(
      xb, Wqv, QVb, vb, bv, bv,
      BS, 2 * E, E, E, E, 2 * E, 1.f, 0, 0, 0);

  // ---- V^T per batch: [2048,1024](ld 2048) -> [1024,2048]
  transpose_bf16<<<dim3(E / 32, S / 32, B), dim3(32, 8), 0, stream>>>(
      QVb + E, VTb, S, E, 2 * E, (long long)S * 2 * E, (long long)E * S);

  // ---- scores' = G . x^T * E^-0.5 per batch (2 blocks/CU TLP)
  gemm128_bt2<bf16_t, 0><<<dim3(S / 128, S / 128, B), 256, 0, stream>>>(
      QVb, xb, Sb, nullptr,
      S, S, E, 2 * E, E, S, 0.03125f,
      (long long)S * 2 * E, (long long)S * E, (long long)S * S);

  // ---- softmax
  softmax_rows<<<BS, 256, 0, stream>>>(Sb, Pb, S);

  // ---- O = P . (V^T)^T per batch  (128^2 tile, 2 blocks/CU)
  gemm128_bt2<bf16_t, 0><<<dim3(E / 128, S / 128, B), 256, 0, stream>>>(
      Pb, VTb, Ob, nullptr,
      S, E, S, S, S, E, 1.f,
      (long long)S * S, (long long)E * S, (long long)S * E);

  // ---- y = O . Wo^T + bo  (128^2 tile, 2 blocks/CU)
  gemm128_bt2<float, 1><<<dim3(E / 128, BS / 128, 1), 256, 0, stream>>>(
      Ob, Wob, out, bo,
      BS, E, E, E, E, E, 1.f, 0, 0, 0);
}